// Round 5
// baseline (1598.298 us; speedup 1.0000x reference)
//
#include <hip/hip_runtime.h>
#include <hip/hip_bf16.h>
#include <cstdint>
#include <cstddef>

typedef unsigned short u16;
typedef unsigned int   u32;
typedef short bf16x8 __attribute__((ext_vector_type(8)));   // 8 bf16 = 4 VGPRs
typedef float f32x4  __attribute__((ext_vector_type(4)));

__device__ __forceinline__ float bf2f(u16 v){ return __uint_as_float(((u32)v)<<16); }
__device__ __forceinline__ u16 f2bf(float f){
  u32 x = __float_as_uint(f);
  return (u16)((x + 0x7FFFu + ((x>>16)&1u)) >> 16);   // round-to-nearest-even
}
__device__ __forceinline__ void atomAddF(float* p, float v){ unsafeAtomicAdd(p, v); }

// ---------------- zero helpers ----------------
__global__ void kzero(float* p, int n){
  int i = blockIdx.x*blockDim.x + threadIdx.x;
  if(i < n) p[i] = 0.f;
}
__global__ void kzero4(float4* p, int n){
  int i = blockIdx.x*blockDim.x + threadIdx.x;
  if(i < n) p[i] = make_float4(0.f,0.f,0.f,0.f);
}

// ---------------- degrees + edge importance ----------------
__global__ void kdeg(const int* __restrict__ ei0, const int* __restrict__ ei1,
                     const float* __restrict__ nimp, int* __restrict__ deg,
                     float* __restrict__ imp, int E){
  int e = blockIdx.x*blockDim.x + threadIdx.x;
  if(e >= E) return;
  int u = ei0[e], v = ei1[e];
  atomicAdd(&deg[u], 1);
  atomicAdd(&deg[v], 1);
  imp[e] = fminf(nimp[u], nimp[v]);
}

__global__ void kdinv(const int* __restrict__ deg, float* __restrict__ dinv, int N){
  int i = blockIdx.x*blockDim.x + threadIdx.x;
  if(i >= N) return;
  int d = deg[i];
  dinv[i] = (d > 1) ? (1.f/(float)d) : 0.f;   // deg==1 hyperedges are dropped
}

// ---------------- W -> fragment-ready layout (bf16) ----------------
// slot s = tt*(NC*64) + c*64 + lane ; elem j: wf[s*8+j] = W[c*32+(lane>>4)*8+j][tt*16+(lane&15)]
template<int DIN>
__global__ void kprepw(const float* __restrict__ W, u16* __restrict__ wf){
  constexpr int NC = DIN/32;
  constexpr int SLOTS = 4*NC*64;
  int s = blockIdx.x*blockDim.x + threadIdx.x;
  if(s >= SLOTS) return;
  int lane = s & 63;
  int c    = (s >> 6) % NC;
  int tt   = s / (NC*64);
  int n  = tt*16 + (lane & 15);
  int k0 = c*32 + (lane >> 4)*8;
  #pragma unroll
  for(int j = 0; j < 8; j++)
    wf[(size_t)s*8 + j] = f2bf(W[(size_t)(k0 + j)*64 + n]);
}

// ---------------- layer 0: MFMA GEMM (edge_attr*imp @ W0) + fused he-scatter ----
__global__ __launch_bounds__(256) void kgemm0(const float* __restrict__ srcf,
                                              u16* __restrict__ buf,
                                              const u16* __restrict__ wf,
                                              const float* __restrict__ imp,
                                              const int* __restrict__ ei0,
                                              const int* __restrict__ ei1,
                                              float* __restrict__ he,
                                              int E){
  const int t    = threadIdx.x;
  const int wv   = t >> 6;
  const int lane = t & 63;
  const int quad = lane >> 4;
  const int l15  = lane & 15;
  const int row0 = blockIdx.x*64 + wv*16;
  if(row0 >= E) return;                      // E % 16 == 0

  bf16x8 bfr[4];
  #pragma unroll
  for(int i = 0; i < 4; i++)
    bfr[i] = *(const bf16x8*)(wf + ((size_t)i*64 + lane)*8);

  const int myrow = row0 + l15;
  const float* s = srcf + (size_t)myrow*32 + quad*8;
  const float sc = imp[myrow];
  f32x4 v0 = *(const f32x4*)s;
  f32x4 v1 = *(const f32x4*)(s+4);
  bf16x8 afr;
  afr[0]=(short)f2bf(v0.x*sc); afr[1]=(short)f2bf(v0.y*sc);
  afr[2]=(short)f2bf(v0.z*sc); afr[3]=(short)f2bf(v0.w*sc);
  afr[4]=(short)f2bf(v1.x*sc); afr[5]=(short)f2bf(v1.y*sc);
  afr[6]=(short)f2bf(v1.z*sc); afr[7]=(short)f2bf(v1.w*sc);

  f32x4 acc[4];
  #pragma unroll
  for(int tt = 0; tt < 4; tt++){
    f32x4 a = {0.f,0.f,0.f,0.f};
    acc[tt] = __builtin_amdgcn_mfma_f32_16x16x32_bf16(afr, bfr[tt], a, 0, 0, 0);
  }

  int us[4], vs[4];
  #pragma unroll
  for(int r = 0; r < 4; r++){
    int em = row0 + quad*4 + r;
    us[r] = ei0[em];
    vs[r] = ei1[em];
  }
  #pragma unroll
  for(int tt = 0; tt < 4; tt++){
    const int n = tt*16 + l15;
    #pragma unroll
    for(int r = 0; r < 4; r++){
      const int em = row0 + quad*4 + r;
      const float val = acc[tt][r];
      buf[(size_t)em*64 + n] = f2bf(val);
      atomAddF(&he[(size_t)us[r]*64 + n], val);
      atomAddF(&he[(size_t)vs[r]*64 + n], val);
    }
  }
}

// ---------------- fused: gather(he_in) + epilogue + pool, then GEMM + scatter ----
// Stage 1 (per wave, rows row0..row0+15, lane = feature d):
//   o = relu((xw + he[u]*iu + he[v]*iv)*rc + b)*imp  -> pool to ghl, bf16 to hT
// Stage 2 (DO_GEMM): hT -> A-frags (LDS transpose), MFMA with W_l, write buf,
//   scatter to he_out.
template<bool DO_GEMM>
__global__ __launch_bounds__(256) void kfused(u16* buf,               // r/w in-place
                                              const float* __restrict__ he_in,
                                              float* __restrict__ he_out,
                                              const u16* __restrict__ wf,
                                              const float* __restrict__ dinv,
                                              const int* __restrict__ ei0,
                                              const int* __restrict__ ei1,
                                              const float* __restrict__ imp,
                                              const float* __restrict__ bias,
                                              const int* __restrict__ batch,
                                              float* __restrict__ ghL,  // gh + layer*64
                                              int E){
  __shared__ float ghl[64*64];
  __shared__ __align__(16) u16 hT[4][1160];   // 16 rows x 72 (stride-padded) per wave
  const int t    = threadIdx.x;
  const int wv   = t >> 6;
  const int lane = t & 63;
  const int quad = lane >> 4;
  const int l15  = lane & 15;
  const int row0 = blockIdx.x*64 + wv*16;
  const bool active = row0 < E;               // E % 16 == 0: wave-granular

  for(int i = t; i < 4096; i += 256) ghl[i] = 0.f;
  __syncthreads();

  int u_l = 0, v_l = 0, g_l = 0;
  float imp_l = 0.f, du_l = 0.f, dv_l = 0.f;
  if(active){
    const int er = row0 + l15;                // replicated across quads
    u_l = ei0[er];  v_l = ei1[er];
    imp_l = imp[er];
    du_l = dinv[u_l]; dv_l = dinv[v_l];
    g_l  = batch[u_l];
    const float bd = bias[lane];

    #pragma unroll
    for(int r = 0; r < 16; r++){
      const int   u  = __shfl(u_l, r, 16);
      const int   v  = __shfl(v_l, r, 16);
      const float iu = __shfl(du_l, r, 16);
      const float iv = __shfl(dv_l, r, 16);
      const float ie = __shfl(imp_l, r, 16);
      const int   g  = __shfl(g_l, r, 16);
      const int   e  = row0 + r;
      float val = bf2f(buf[(size_t)e*64 + lane]);
      val += he_in[(size_t)u*64 + lane] * iu;
      val += he_in[(size_t)v*64 + lane] * iv;
      const float rc = (iu > 0.f && iv > 0.f) ? (1.f/3.f)
                     : ((iu > 0.f || iv > 0.f) ? 0.5f : 1.f);
      const float o = fmaxf(val*rc + bd, 0.f) * ie;
      atomicAdd(&ghl[g*64 + lane], o);
      if(DO_GEMM) hT[wv][r*72 + lane] = f2bf(o);
    }
  }
  __syncthreads();

  if(DO_GEMM && active){
    bf16x8 afr[2];
    #pragma unroll
    for(int c = 0; c < 2; c++)
      afr[c] = *(const bf16x8*)&hT[wv][l15*72 + c*32 + quad*8];
    bf16x8 bfr[8];
    #pragma unroll
    for(int i = 0; i < 8; i++)
      bfr[i] = *(const bf16x8*)(wf + ((size_t)i*64 + lane)*8);

    f32x4 acc[4];
    #pragma unroll
    for(int tt = 0; tt < 4; tt++){
      f32x4 a = {0.f,0.f,0.f,0.f};
      a = __builtin_amdgcn_mfma_f32_16x16x32_bf16(afr[0], bfr[tt*2+0], a, 0, 0, 0);
      a = __builtin_amdgcn_mfma_f32_16x16x32_bf16(afr[1], bfr[tt*2+1], a, 0, 0, 0);
      acc[tt] = a;
    }
    #pragma unroll
    for(int tt = 0; tt < 4; tt++){
      const int n = tt*16 + l15;
      #pragma unroll
      for(int r = 0; r < 4; r++){
        const int em  = row0 + quad*4 + r;
        const int u   = __shfl(u_l, quad*4 + r, 16);
        const int v   = __shfl(v_l, quad*4 + r, 16);
        const float val = acc[tt][r];
        buf[(size_t)em*64 + n] = f2bf(val);
        atomAddF(&he_out[(size_t)u*64 + n], val);
        atomAddF(&he_out[(size_t)v*64 + n], val);
      }
    }
  }

  // flush pooled partials (all threads; ghl complete after barrier above)
  for(int i = t; i < 4096; i += 256){
    float v2 = ghl[i];
    if(v2 != 0.f) atomAddF(&ghL[(i>>6)*192 + (i&63)], v2);
  }
}

__global__ void kfinal(const float* __restrict__ gh, float* __restrict__ out, int n){
  int i = blockIdx.x*blockDim.x + threadIdx.x;
  if(i < n) out[i] = gh[i];   // reference output dtype = float32
}

// ---------------- host ----------------
extern "C" void kernel_launch(void* const* d_in, const int* in_sizes, int n_in,
                              void* d_out, int out_size, void* d_ws, size_t ws_size,
                              hipStream_t stream) {
  const float* edge_attr = (const float*)d_in[1];
  const int*   ei        = (const int*)d_in[2];
  const int*   batch     = (const int*)d_in[3];
  const float* nimp      = (const float*)d_in[4];
  const float* Ws[3] = { (const float*)d_in[5], (const float*)d_in[7], (const float*)d_in[9] };
  const float* bs[3] = { (const float*)d_in[6], (const float*)d_in[8], (const float*)d_in[10] };

  const int E = in_sizes[1] / 32;   // edge_attr is (E, 32)
  const int N = in_sizes[4];        // node_imp is (N,)
  const int* ei0 = ei;
  const int* ei1 = ei + E;

  char* p = (char*)d_ws;
  auto carve = [&](size_t bytes)->char*{
    char* r = p; p += (bytes + 255) & ~(size_t)255; return r;
  };
  float* imp  = (float*)carve((size_t)E*4);
  int*   deg  = (int*)  carve((size_t)N*4);
  float* dinv = (float*)carve((size_t)N*4);
  float* he0  = (float*)carve((size_t)N*64*4);
  float* he1  = (float*)carve((size_t)N*64*4);
  u16*   buf  = (u16*)  carve((size_t)E*64*2);   // xw, rewritten per layer
  float* gh   = (float*)carve((size_t)64*192*4);
  u16*   wfs[3];
  for(int l = 0; l < 3; l++) wfs[l] = (u16*)carve((size_t)4096*2);

  kzero<<<(N+255)/256, 256, 0, stream>>>((float*)deg, N);
  kzero<<<(12288+255)/256, 256, 0, stream>>>(gh, 12288);
  kdeg<<<(E+255)/256, 256, 0, stream>>>(ei0, ei1, nimp, deg, imp, E);
  kdinv<<<(N+255)/256, 256, 0, stream>>>(deg, dinv, N);
  kprepw<32><<<1, 256, 0, stream>>>(Ws[0], wfs[0]);
  kprepw<64><<<2, 256, 0, stream>>>(Ws[1], wfs[1]);
  kprepw<64><<<2, 256, 0, stream>>>(Ws[2], wfs[2]);

  const int he4 = N*64/4;                         // float4 count per he buffer
  const int nb  = (E + 63)/64;
  // zero he0+he1 (contiguous)
  kzero4<<<(2*he4+255)/256, 256, 0, stream>>>((float4*)he0, 2*he4);
  // L0: xw0 = (edge_attr*imp)@W0, scatter -> he0
  kgemm0<<<nb, 256, 0, stream>>>(edge_attr, buf, wfs[0], imp, ei0, ei1, he0, E);
  // F1: gather he0 -> h'0 (pool gh[:,0:64]); xw1 = h'0@W1; scatter -> he1
  kfused<true ><<<nb, 256, 0, stream>>>(buf, he0, he1, wfs[1], dinv, ei0, ei1, imp,
                                        bs[0], batch, gh + 0*64, E);
  // re-zero he0 for reuse as layer-2 scatter target
  kzero4<<<(he4+255)/256, 256, 0, stream>>>((float4*)he0, he4);
  // F2: gather he1 -> h'1 (pool gh[:,64:128]); xw2 = h'1@W2; scatter -> he0
  kfused<true ><<<nb, 256, 0, stream>>>(buf, he1, he0, wfs[2], dinv, ei0, ei1, imp,
                                        bs[1], batch, gh + 1*64, E);
  // F3: gather he0 -> h'2, pool gh[:,128:192] only
  kfused<false><<<nb, 256, 0, stream>>>(buf, he0, nullptr, nullptr, dinv, ei0, ei1, imp,
                                        bs[2], batch, gh + 2*64, E);
  kfinal<<<(12288+255)/256, 256, 0, stream>>>(gh, (float*)d_out, 12288);
}

// Round 6
// 1048.539 us; speedup vs baseline: 1.5243x; 1.5243x over previous
//
#include <hip/hip_runtime.h>
#include <hip/hip_bf16.h>
#include <cstdint>
#include <cstddef>

typedef unsigned short u16;
typedef unsigned int   u32;
typedef short bf16x8 __attribute__((ext_vector_type(8)));   // 8 bf16 = 4 VGPRs
typedef float f32x4  __attribute__((ext_vector_type(4)));

__device__ __forceinline__ float bf2f(u16 v){ return __uint_as_float(((u32)v)<<16); }
__device__ __forceinline__ u16 f2bf(float f){
  u32 x = __float_as_uint(f);
  return (u16)((x + 0x7FFFu + ((x>>16)&1u)) >> 16);   // round-to-nearest-even
}
__device__ __forceinline__ void atomAddF(float* p, float v){ unsafeAtomicAdd(p, v); }

// ---------------- zero helper ----------------
__global__ void kzero(int* p, int n){
  int i = blockIdx.x*blockDim.x + threadIdx.x;
  if(i < n) p[i] = 0;
}

// ---------------- degrees + edge importance ----------------
__global__ void kdeg(const int* __restrict__ ei0, const int* __restrict__ ei1,
                     const float* __restrict__ nimp, int* __restrict__ deg,
                     float* __restrict__ imp, int E){
  int e = blockIdx.x*blockDim.x + threadIdx.x;
  if(e >= E) return;
  int u = ei0[e], v = ei1[e];
  atomicAdd(&deg[u], 1);
  atomicAdd(&deg[v], 1);
  imp[e] = fminf(nimp[u], nimp[v]);
}

__global__ void kdinv(const int* __restrict__ deg, float* __restrict__ dinv, int N){
  int i = blockIdx.x*blockDim.x + threadIdx.x;
  if(i >= N) return;
  int d = deg[i];
  dinv[i] = (d > 1) ? (1.f/(float)d) : 0.f;   // deg==1 hyperedges dropped
}

// ---------------- exclusive prefix scan of deg -> off (1 block, 1024 thr) ------
__global__ __launch_bounds__(1024) void kscan(const int* __restrict__ deg,
                                              int* __restrict__ off, int N){
  __shared__ int part[1024];
  const int t = threadIdx.x;
  const int per = (N + 1023)/1024;
  const int start = t*per, end = min(start+per, N);
  int s = 0;
  for(int i = start; i < end; i++) s += deg[i];
  part[t] = s;
  __syncthreads();
  for(int d = 1; d < 1024; d <<= 1){
    int v = (t >= d) ? part[t-d] : 0;
    __syncthreads();
    part[t] += v;
    __syncthreads();
  }
  int run = (t == 0) ? 0 : part[t-1];
  for(int i = start; i < end; i++){ off[i] = run; run += deg[i]; }
  if(t == 1023) off[N] = run;          // == 2E
}

// ---------------- CSR fill: node -> incident edge ids ----------------
__global__ void kfill(const int* __restrict__ ei0, const int* __restrict__ ei1,
                      const int* __restrict__ off, int* __restrict__ cursor,
                      int* __restrict__ list, int E){
  int e = blockIdx.x*blockDim.x + threadIdx.x;
  if(e >= E) return;
  int u = ei0[e], v = ei1[e];
  int p = atomicAdd(&cursor[u], 1); list[off[u] + p] = e;
  int q = atomicAdd(&cursor[v], 1); list[off[v] + q] = e;
}

// ---------------- W -> fragment-ready layout (bf16) ----------------
template<int DIN>
__global__ void kprepw(const float* __restrict__ W, u16* __restrict__ wf){
  constexpr int NC = DIN/32;
  constexpr int SLOTS = 4*NC*64;
  int s = blockIdx.x*blockDim.x + threadIdx.x;
  if(s >= SLOTS) return;
  int lane = s & 63;
  int c    = (s >> 6) % NC;
  int tt   = s / (NC*64);
  int n  = tt*16 + (lane & 15);
  int k0 = c*32 + (lane >> 4)*8;
  #pragma unroll
  for(int j = 0; j < 8; j++)
    wf[(size_t)s*8 + j] = f2bf(W[(size_t)(k0 + j)*64 + n]);
}

// ---------------- pure MFMA GEMM: buf[e][:] = h[e][:] @ W ----------------
template<int DIN, bool FIRST>
__global__ __launch_bounds__(256) void kgemm(const float* __restrict__ srcf,
                                             u16* buf,              // r/w in-place
                                             const u16* __restrict__ wf,
                                             const float* __restrict__ imp,
                                             int E){
  constexpr int NC = DIN/32;
  const int t    = threadIdx.x;
  const int wv   = t >> 6;
  const int lane = t & 63;
  const int quad = lane >> 4;
  const int l15  = lane & 15;
  const int row0 = blockIdx.x*64 + wv*16;
  if(row0 >= E) return;                      // E % 16 == 0

  bf16x8 bfr[4*NC];
  #pragma unroll
  for(int i = 0; i < 4*NC; i++)
    bfr[i] = *(const bf16x8*)(wf + ((size_t)i*64 + lane)*8);

  const int myrow = row0 + l15;
  bf16x8 afr[NC];
  if(FIRST){
    const float* s = srcf + (size_t)myrow*32 + quad*8;
    const float sc = imp[myrow];
    f32x4 v0 = *(const f32x4*)s;
    f32x4 v1 = *(const f32x4*)(s+4);
    bf16x8 a;
    a[0]=(short)f2bf(v0.x*sc); a[1]=(short)f2bf(v0.y*sc);
    a[2]=(short)f2bf(v0.z*sc); a[3]=(short)f2bf(v0.w*sc);
    a[4]=(short)f2bf(v1.x*sc); a[5]=(short)f2bf(v1.y*sc);
    a[6]=(short)f2bf(v1.z*sc); a[7]=(short)f2bf(v1.w*sc);
    afr[0] = a;
  } else {
    #pragma unroll
    for(int c = 0; c < NC; c++)
      afr[c] = *(const bf16x8*)(buf + (size_t)myrow*64 + c*32 + quad*8);
  }

  f32x4 acc[4];
  #pragma unroll
  for(int tt = 0; tt < 4; tt++){
    f32x4 a = {0.f,0.f,0.f,0.f};
    #pragma unroll
    for(int c = 0; c < NC; c++)
      a = __builtin_amdgcn_mfma_f32_16x16x32_bf16(afr[c], bfr[tt*NC+c], a, 0, 0, 0);
    acc[tt] = a;
  }

  #pragma unroll
  for(int tt = 0; tt < 4; tt++){
    const int n = tt*16 + l15;
    #pragma unroll
    for(int r = 0; r < 4; r++)
      buf[(size_t)(row0 + quad*4 + r)*64 + n] = f2bf(acc[tt][r]);
  }
}

// ---------------- CSR aggregate: he[n][:] = sum_{e in inc(n)} xw[e][:] --------
__global__ __launch_bounds__(256) void kagg(const u16* __restrict__ buf,
                                            const int* __restrict__ off,
                                            const int* __restrict__ list,
                                            float* __restrict__ he, int N){
  const int t = threadIdx.x, wv = t >> 6, lane = t & 63;
  const int n = blockIdx.x*4 + wv;
  if(n >= N) return;
  int j = off[n];
  const int end = off[n+1];
  float s = 0.f;
  for(; j + 3 < end; j += 4){
    int e0 = list[j], e1 = list[j+1], e2 = list[j+2], e3 = list[j+3];
    float a0 = bf2f(buf[(size_t)e0*64 + lane]);
    float a1 = bf2f(buf[(size_t)e1*64 + lane]);
    float a2 = bf2f(buf[(size_t)e2*64 + lane]);
    float a3 = bf2f(buf[(size_t)e3*64 + lane]);
    s += a0 + a1 + a2 + a3;
  }
  for(; j < end; j++) s += bf2f(buf[(size_t)list[j]*64 + lane]);
  he[(size_t)n*64 + lane] = s;
}

// ---------------- gather + epilogue + pool (4 edges in flight per wave) -------
__global__ __launch_bounds__(256) void kgather(u16* buf,          // read xw, write h'
                                               const float* __restrict__ he,
                                               const float* __restrict__ dinv,
                                               const int* __restrict__ ei0,
                                               const int* __restrict__ ei1,
                                               const float* __restrict__ imp,
                                               const float* __restrict__ bias,
                                               const int* __restrict__ batch,
                                               float* __restrict__ ghL,  // gh + layer*64
                                               int E){
  __shared__ float ghl[4096];
  const int t = threadIdx.x;
  for(int i = t; i < 4096; i += 256) ghl[i] = 0.f;
  __syncthreads();
  const int d = t & 63, wv = t >> 6;
  const float bd = bias[d];

  for(int base = blockIdx.x*16 + wv*4; base < E; base += gridDim.x*16){
    int u4[4], v4[4], g4[4];
    float iu4[4], iv4[4], ie4[4], bv[4], hu[4], hv[4];
    #pragma unroll
    for(int q = 0; q < 4; q++){ u4[q] = ei0[base+q]; v4[q] = ei1[base+q]; }
    #pragma unroll
    for(int q = 0; q < 4; q++){
      bv[q]  = bf2f(buf[(size_t)(base+q)*64 + d]);
      hu[q]  = he[(size_t)u4[q]*64 + d];
      hv[q]  = he[(size_t)v4[q]*64 + d];
      iu4[q] = dinv[u4[q]];
      iv4[q] = dinv[v4[q]];
      ie4[q] = imp[base+q];
      g4[q]  = batch[u4[q]];
    }
    #pragma unroll
    for(int q = 0; q < 4; q++){
      float val = bv[q] + hu[q]*iu4[q] + hv[q]*iv4[q];
      float rc = (iu4[q] > 0.f && iv4[q] > 0.f) ? (1.f/3.f)
               : ((iu4[q] > 0.f || iv4[q] > 0.f) ? 0.5f : 1.f);
      float o = fmaxf(val*rc + bd, 0.f) * ie4[q];
      buf[(size_t)(base+q)*64 + d] = f2bf(o);
      atomicAdd(&ghl[g4[q]*64 + d], o);
    }
  }
  __syncthreads();
  for(int i = t; i < 4096; i += 256){
    float v = ghl[i];
    if(v != 0.f) atomAddF(&ghL[(i>>6)*192 + (i&63)], v);
  }
}

__global__ void kfinal(const float* __restrict__ gh, float* __restrict__ out, int n){
  int i = blockIdx.x*blockDim.x + threadIdx.x;
  if(i < n) out[i] = gh[i];   // reference output dtype = float32
}

// ---------------- host ----------------
extern "C" void kernel_launch(void* const* d_in, const int* in_sizes, int n_in,
                              void* d_out, int out_size, void* d_ws, size_t ws_size,
                              hipStream_t stream) {
  const float* edge_attr = (const float*)d_in[1];
  const int*   ei        = (const int*)d_in[2];
  const int*   batch     = (const int*)d_in[3];
  const float* nimp      = (const float*)d_in[4];
  const float* Ws[3] = { (const float*)d_in[5], (const float*)d_in[7], (const float*)d_in[9] };
  const float* bs[3] = { (const float*)d_in[6], (const float*)d_in[8], (const float*)d_in[10] };

  const int E = in_sizes[1] / 32;   // edge_attr is (E, 32)
  const int N = in_sizes[4];        // node_imp is (N,)
  const int* ei0 = ei;
  const int* ei1 = ei + E;

  char* p = (char*)d_ws;
  auto carve = [&](size_t bytes)->char*{
    char* r = p; p += (bytes + 255) & ~(size_t)255; return r;
  };
  float* imp    = (float*)carve((size_t)E*4);
  int*   deg    = (int*)  carve((size_t)2*N*4);   // deg | cursor (contiguous for 1 zero)
  int*   cursor = deg + N;
  float* dinv   = (float*)carve((size_t)N*4);
  int*   off    = (int*)  carve((size_t)(N+1)*4);
  int*   list   = (int*)  carve((size_t)2*E*4);
  float* he     = (float*)carve((size_t)N*64*4);
  u16*   buf    = (u16*)  carve((size_t)E*64*2);  // xw / h' in-place
  float* gh     = (float*)carve((size_t)64*192*4);
  u16*   wfs[3];
  for(int l = 0; l < 3; l++) wfs[l] = (u16*)carve((size_t)4096*2);

  kzero<<<(2*N+255)/256, 256, 0, stream>>>(deg, 2*N);
  kzero<<<(12288+255)/256, 256, 0, stream>>>((int*)gh, 12288);
  kdeg<<<(E+255)/256, 256, 0, stream>>>(ei0, ei1, nimp, deg, imp, E);
  kscan<<<1, 1024, 0, stream>>>(deg, off, N);
  kdinv<<<(N+255)/256, 256, 0, stream>>>(deg, dinv, N);
  kfill<<<(E+255)/256, 256, 0, stream>>>(ei0, ei1, off, cursor, list, E);
  kprepw<32><<<1, 256, 0, stream>>>(Ws[0], wfs[0]);
  kprepw<64><<<2, 256, 0, stream>>>(Ws[1], wfs[1]);
  kprepw<64><<<2, 256, 0, stream>>>(Ws[2], wfs[2]);

  const int nbG = (E + 63)/64;
  const int nbA = (N + 3)/4;
  for(int l = 0; l < 3; l++){
    if(l == 0) kgemm<32,true ><<<nbG, 256, 0, stream>>>(edge_attr, buf, wfs[0], imp, E);
    else       kgemm<64,false><<<nbG, 256, 0, stream>>>(nullptr,   buf, wfs[l], imp, E);
    kagg<<<nbA, 256, 0, stream>>>(buf, off, list, he, N);
    kgather<<<1024, 256, 0, stream>>>(buf, he, dinv, ei0, ei1, imp, bs[l], batch,
                                      gh + l*64, E);
  }
  kfinal<<<(12288+255)/256, 256, 0, stream>>>(gh, (float*)d_out, 12288);
}

// Round 7
// 993.696 us; speedup vs baseline: 1.6084x; 1.0552x over previous
//
#include <hip/hip_runtime.h>
#include <hip/hip_bf16.h>
#include <cstdint>
#include <cstddef>

typedef unsigned short u16;
typedef unsigned int   u32;
typedef short bf16x8 __attribute__((ext_vector_type(8)));   // 8 bf16 = 4 VGPRs
typedef float f32x4  __attribute__((ext_vector_type(4)));

__device__ __forceinline__ float bf2f(u16 v){ return __uint_as_float(((u32)v)<<16); }
__device__ __forceinline__ u16 f2bf(float f){
  u32 x = __float_as_uint(f);
  return (u16)((x + 0x7FFFu + ((x>>16)&1u)) >> 16);   // round-to-nearest-even
}
__device__ __forceinline__ void atomAddF(float* p, float v){ unsafeAtomicAdd(p, v); }

// ---------------- zero helper ----------------
__global__ void kzero(int* p, int n){
  int i = blockIdx.x*blockDim.x + threadIdx.x;
  if(i < n) p[i] = 0;
}

// ---------------- degrees + edge importance ----------------
__global__ void kdeg(const int* __restrict__ ei0, const int* __restrict__ ei1,
                     const float* __restrict__ nimp, int* __restrict__ deg,
                     float* __restrict__ imp, int E){
  int e = blockIdx.x*blockDim.x + threadIdx.x;
  if(e >= E) return;
  int u = ei0[e], v = ei1[e];
  atomicAdd(&deg[u], 1);
  atomicAdd(&deg[v], 1);
  imp[e] = fminf(nimp[u], nimp[v]);
}

__global__ void kdinv(const int* __restrict__ deg, float* __restrict__ dinv, int N){
  int i = blockIdx.x*blockDim.x + threadIdx.x;
  if(i >= N) return;
  int d = deg[i];
  dinv[i] = (d > 1) ? (1.f/(float)d) : 0.f;   // deg==1 hyperedges dropped
}

// ---------------- exclusive prefix scan of deg -> off (1 block) ----------------
__global__ __launch_bounds__(1024) void kscan(const int* __restrict__ deg,
                                              int* __restrict__ off, int N){
  __shared__ int part[1024];
  const int t = threadIdx.x;
  const int per = (N + 1023)/1024;
  const int start = t*per, end = min(start+per, N);
  int s = 0;
  for(int i = start; i < end; i++) s += deg[i];
  part[t] = s;
  __syncthreads();
  for(int d = 1; d < 1024; d <<= 1){
    int v = (t >= d) ? part[t-d] : 0;
    __syncthreads();
    part[t] += v;
    __syncthreads();
  }
  int run = (t == 0) ? 0 : part[t-1];
  for(int i = start; i < end; i++){ off[i] = run; run += deg[i]; }
  if(t == 1023) off[N] = run;          // == 2E
}

// ---------------- CSR fill: node -> incident edge ids ----------------
__global__ void kfill(const int* __restrict__ ei0, const int* __restrict__ ei1,
                      const int* __restrict__ off, int* __restrict__ cursor,
                      int* __restrict__ list, int E){
  int e = blockIdx.x*blockDim.x + threadIdx.x;
  if(e >= E) return;
  int u = ei0[e], v = ei1[e];
  int p = atomicAdd(&cursor[u], 1); list[off[u] + p] = e;
  int q = atomicAdd(&cursor[v], 1); list[off[v] + q] = e;
}

// ---------------- W -> fragment-ready layout (bf16) ----------------
template<int DIN>
__global__ void kprepw(const float* __restrict__ W, u16* __restrict__ wf){
  constexpr int NC = DIN/32;
  constexpr int SLOTS = 4*NC*64;
  int s = blockIdx.x*blockDim.x + threadIdx.x;
  if(s >= SLOTS) return;
  int lane = s & 63;
  int c    = (s >> 6) % NC;
  int tt   = s / (NC*64);
  int n  = tt*16 + (lane & 15);
  int k0 = c*32 + (lane >> 4)*8;
  #pragma unroll
  for(int j = 0; j < 8; j++)
    wf[(size_t)s*8 + j] = f2bf(W[(size_t)(k0 + j)*64 + n]);
}

// ---------------- layer 0: pure MFMA GEMM (edge_attr*imp @ W0) ----------------
__global__ __launch_bounds__(256) void kgemm0(const float* __restrict__ srcf,
                                              u16* __restrict__ buf,
                                              const u16* __restrict__ wf,
                                              const float* __restrict__ imp,
                                              int E){
  const int t    = threadIdx.x;
  const int wv   = t >> 6;
  const int lane = t & 63;
  const int quad = lane >> 4;
  const int l15  = lane & 15;
  const int row0 = blockIdx.x*64 + wv*16;
  if(row0 >= E) return;                      // E % 16 == 0

  bf16x8 bfr[4];
  #pragma unroll
  for(int i = 0; i < 4; i++)
    bfr[i] = *(const bf16x8*)(wf + ((size_t)i*64 + lane)*8);

  const int myrow = row0 + l15;
  const float* s = srcf + (size_t)myrow*32 + quad*8;
  const float sc = imp[myrow];
  f32x4 v0 = *(const f32x4*)s;
  f32x4 v1 = *(const f32x4*)(s+4);
  bf16x8 afr;
  afr[0]=(short)f2bf(v0.x*sc); afr[1]=(short)f2bf(v0.y*sc);
  afr[2]=(short)f2bf(v0.z*sc); afr[3]=(short)f2bf(v0.w*sc);
  afr[4]=(short)f2bf(v1.x*sc); afr[5]=(short)f2bf(v1.y*sc);
  afr[6]=(short)f2bf(v1.z*sc); afr[7]=(short)f2bf(v1.w*sc);

  #pragma unroll
  for(int tt = 0; tt < 4; tt++){
    f32x4 a = {0.f,0.f,0.f,0.f};
    a = __builtin_amdgcn_mfma_f32_16x16x32_bf16(afr, bfr[tt], a, 0, 0, 0);
    const int n = tt*16 + l15;
    #pragma unroll
    for(int r = 0; r < 4; r++)
      buf[(size_t)(row0 + quad*4 + r)*64 + n] = f2bf(a[r]);
  }
}

// ---------------- CSR aggregate: he[n][:] = sum_{e in inc(n)} xw[e][:] --------
__global__ __launch_bounds__(256) void kagg(const u16* __restrict__ buf,
                                            const int* __restrict__ off,
                                            const int* __restrict__ list,
                                            float* __restrict__ he, int N){
  const int t = threadIdx.x, wv = t >> 6, lane = t & 63;
  const int n = blockIdx.x*4 + wv;
  if(n >= N) return;
  int j = off[n];
  const int end = off[n+1];
  float s = 0.f;
  for(; j + 3 < end; j += 4){
    int e0 = list[j], e1 = list[j+1], e2 = list[j+2], e3 = list[j+3];
    float a0 = bf2f(buf[(size_t)e0*64 + lane]);
    float a1 = bf2f(buf[(size_t)e1*64 + lane]);
    float a2 = bf2f(buf[(size_t)e2*64 + lane]);
    float a3 = bf2f(buf[(size_t)e3*64 + lane]);
    s += a0 + a1 + a2 + a3;
  }
  for(; j < end; j++) s += bf2f(buf[(size_t)list[j]*64 + lane]);
  he[(size_t)n*64 + lane] = s;
}

// ---------------- fused: gather + epilogue + pool (+ next-layer GEMM) ----------
// Each wave owns 16 rows per iteration: stage-1 gathers/epilogues them (ILP-4,
// R6-kgather pattern), h' -> wave-private LDS; stage-2 (DO_GEMM) MFMAs those
// same 16 rows from LDS (no inter-wave barrier needed in the loop).
template<bool DO_GEMM>
__global__ __launch_bounds__(256) void kfused(u16* buf,               // r/w
                                              const float* __restrict__ he,
                                              const float* __restrict__ dinv,
                                              const int* __restrict__ ei0,
                                              const int* __restrict__ ei1,
                                              const float* __restrict__ imp,
                                              const float* __restrict__ bias,
                                              const int* __restrict__ batch,
                                              const u16* __restrict__ wf,
                                              float* __restrict__ ghL,  // gh + layer*64
                                              int E){
  __shared__ float ghl[4096];                       // 16 KB graph pool
  constexpr int HTSZ = DO_GEMM ? 4*16*68 : 4;       // 16 rows x 68 (pad) per wave
  __shared__ __align__(16) u16 hT[HTSZ];
  const int t = threadIdx.x, wv = t >> 6, lane = t & 63;
  const int quad = lane >> 4, l15 = lane & 15;
  for(int i = t; i < 4096; i += 256) ghl[i] = 0.f;
  __syncthreads();
  const float bd = bias[lane];

  bf16x8 bfr[8];
  if(DO_GEMM){
    #pragma unroll
    for(int i = 0; i < 8; i++)
      bfr[i] = *(const bf16x8*)(wf + ((size_t)i*64 + lane)*8);
  }

  for(int base = blockIdx.x*64; base < E; base += gridDim.x*64){
    const int r0 = base + wv*16;
    if(r0 < E){                                   // E % 16 == 0
      // ---- stage 1: gather + epilogue, 4 groups of 4 edges ----
      #pragma unroll
      for(int g = 0; g < 4; g++){
        const int e0 = r0 + g*4;
        int u4[4], v4[4], g4[4];
        float iu4[4], iv4[4], ie4[4], bv[4], hu[4], hv[4];
        #pragma unroll
        for(int q = 0; q < 4; q++){ u4[q] = ei0[e0+q]; v4[q] = ei1[e0+q]; }
        #pragma unroll
        for(int q = 0; q < 4; q++){
          bv[q]  = bf2f(buf[(size_t)(e0+q)*64 + lane]);
          hu[q]  = he[(size_t)u4[q]*64 + lane];
          hv[q]  = he[(size_t)v4[q]*64 + lane];
          iu4[q] = dinv[u4[q]];
          iv4[q] = dinv[v4[q]];
          ie4[q] = imp[e0+q];
          g4[q]  = batch[u4[q]];
        }
        #pragma unroll
        for(int q = 0; q < 4; q++){
          float val = bv[q] + hu[q]*iu4[q] + hv[q]*iv4[q];
          float rc = (iu4[q] > 0.f && iv4[q] > 0.f) ? (1.f/3.f)
                   : ((iu4[q] > 0.f || iv4[q] > 0.f) ? 0.5f : 1.f);
          float o = fmaxf(val*rc + bd, 0.f) * ie4[q];
          atomicAdd(&ghl[g4[q]*64 + lane], o);
          if(DO_GEMM) hT[wv*1088 + (g*4+q)*68 + lane] = f2bf(o);
        }
      }
      // ---- stage 2: MFMA these 16 rows (wave-local LDS, no barrier) ----
      if(DO_GEMM){
        bf16x8 afr0 = *(const bf16x8*)&hT[wv*1088 + l15*68 + quad*8];
        bf16x8 afr1 = *(const bf16x8*)&hT[wv*1088 + l15*68 + 32 + quad*8];
        #pragma unroll
        for(int tt = 0; tt < 4; tt++){
          f32x4 a = {0.f,0.f,0.f,0.f};
          a = __builtin_amdgcn_mfma_f32_16x16x32_bf16(afr0, bfr[tt*2+0], a, 0, 0, 0);
          a = __builtin_amdgcn_mfma_f32_16x16x32_bf16(afr1, bfr[tt*2+1], a, 0, 0, 0);
          const int n = tt*16 + l15;
          #pragma unroll
          for(int r = 0; r < 4; r++)
            buf[(size_t)(r0 + quad*4 + r)*64 + n] = f2bf(a[r]);
        }
      }
    }
  }
  __syncthreads();
  for(int i = t; i < 4096; i += 256){
    float v = ghl[i];
    if(v != 0.f) atomAddF(&ghL[(i>>6)*192 + (i&63)], v);
  }
}

__global__ void kfinal(const float* __restrict__ gh, float* __restrict__ out, int n){
  int i = blockIdx.x*blockDim.x + threadIdx.x;
  if(i < n) out[i] = gh[i];   // reference output dtype = float32
}

// ---------------- host ----------------
extern "C" void kernel_launch(void* const* d_in, const int* in_sizes, int n_in,
                              void* d_out, int out_size, void* d_ws, size_t ws_size,
                              hipStream_t stream) {
  const float* edge_attr = (const float*)d_in[1];
  const int*   ei        = (const int*)d_in[2];
  const int*   batch     = (const int*)d_in[3];
  const float* nimp      = (const float*)d_in[4];
  const float* Ws[3] = { (const float*)d_in[5], (const float*)d_in[7], (const float*)d_in[9] };
  const float* bs[3] = { (const float*)d_in[6], (const float*)d_in[8], (const float*)d_in[10] };

  const int E = in_sizes[1] / 32;   // edge_attr is (E, 32)
  const int N = in_sizes[4];        // node_imp is (N,)
  const int* ei0 = ei;
  const int* ei1 = ei + E;

  char* p = (char*)d_ws;
  auto carve = [&](size_t bytes)->char*{
    char* r = p; p += (bytes + 255) & ~(size_t)255; return r;
  };
  float* imp    = (float*)carve((size_t)E*4);
  int*   deg    = (int*)  carve((size_t)2*N*4);   // deg | cursor
  int*   cursor = deg + N;
  float* dinv   = (float*)carve((size_t)N*4);
  int*   off    = (int*)  carve((size_t)(N+1)*4);
  int*   list   = (int*)  carve((size_t)2*E*4);
  float* he     = (float*)carve((size_t)N*64*4);
  u16*   buf    = (u16*)  carve((size_t)E*64*2);  // xw / h' in-place
  float* gh     = (float*)carve((size_t)64*192*4);
  u16*   wfs[3];
  for(int l = 0; l < 3; l++) wfs[l] = (u16*)carve((size_t)4096*2);

  kzero<<<(2*N+255)/256, 256, 0, stream>>>(deg, 2*N);
  kzero<<<(12288+255)/256, 256, 0, stream>>>((int*)gh, 12288);
  kdeg<<<(E+255)/256, 256, 0, stream>>>(ei0, ei1, nimp, deg, imp, E);
  kscan<<<1, 1024, 0, stream>>>(deg, off, N);
  kdinv<<<(N+255)/256, 256, 0, stream>>>(deg, dinv, N);
  kfill<<<(E+255)/256, 256, 0, stream>>>(ei0, ei1, off, cursor, list, E);
  kprepw<32><<<1, 256, 0, stream>>>(Ws[0], wfs[0]);
  kprepw<64><<<2, 256, 0, stream>>>(Ws[1], wfs[1]);
  kprepw<64><<<2, 256, 0, stream>>>(Ws[2], wfs[2]);

  const int nbG  = (E + 63)/64;
  const int nbA  = (N + 3)/4;
  const int nbF  = 1536;   // 6 blocks/CU (LDS ~25 KB) — full residency
  const int nbF3 = 2048;   // 8 blocks/CU (LDS 16 KB)

  // L0 GEMM
  kgemm0<<<nbG, 256, 0, stream>>>(edge_attr, buf, wfs[0], imp, E);
  // boundary 0: agg -> fused(gather l0 + pool gh0 + GEMM W1)
  kagg<<<nbA, 256, 0, stream>>>(buf, off, list, he, N);
  kfused<true ><<<nbF, 256, 0, stream>>>(buf, he, dinv, ei0, ei1, imp, bs[0], batch,
                                         wfs[1], gh + 0*64, E);
  // boundary 1
  kagg<<<nbA, 256, 0, stream>>>(buf, off, list, he, N);
  kfused<true ><<<nbF, 256, 0, stream>>>(buf, he, dinv, ei0, ei1, imp, bs[1], batch,
                                         wfs[2], gh + 1*64, E);
  // boundary 2: pool only
  kagg<<<nbA, 256, 0, stream>>>(buf, off, list, he, N);
  kfused<false><<<nbF3, 256, 0, stream>>>(buf, he, dinv, ei0, ei1, imp, bs[2], batch,
                                          nullptr, gh + 2*64, E);
  kfinal<<<(12288+255)/256, 256, 0, stream>>>(gh, (float*)d_out, 12288);
}

// Round 8
// 962.508 us; speedup vs baseline: 1.6606x; 1.0324x over previous
//
#include <hip/hip_runtime.h>
#include <hip/hip_bf16.h>
#include <cstdint>
#include <cstddef>

typedef unsigned short u16;
typedef unsigned int   u32;
typedef short bf16x8 __attribute__((ext_vector_type(8)));   // 8 bf16 = 4 VGPRs
typedef float f32x4  __attribute__((ext_vector_type(4)));

__device__ __forceinline__ float bf2f(u16 v){ return __uint_as_float(((u32)v)<<16); }
__device__ __forceinline__ u16 f2bf(float f){
  u32 x = __float_as_uint(f);
  return (u16)((x + 0x7FFFu + ((x>>16)&1u)) >> 16);   // round-to-nearest-even
}
__device__ __forceinline__ void atomAddF(float* p, float v){ unsafeAtomicAdd(p, v); }

// ---------------- zero helper ----------------
__global__ void kzero(int* p, int n){
  int i = blockIdx.x*blockDim.x + threadIdx.x;
  if(i < n) p[i] = 0;
}

// ---------------- per-side degree counts ----------------
__global__ void kdeg2(const int* __restrict__ ei0, const int* __restrict__ ei1,
                      int* __restrict__ deg0, int* __restrict__ deg1, int E){
  int e = blockIdx.x*blockDim.x + threadIdx.x;
  if(e >= E) return;
  atomicAdd(&deg0[ei0[e]], 1);
  atomicAdd(&deg1[ei1[e]], 1);
}

// ---------------- dual exclusive prefix scan (block 0: deg0, block 1: deg1) ----
__global__ __launch_bounds__(1024) void kscan2(const int* __restrict__ deg0,
                                               int* __restrict__ off0,
                                               const int* __restrict__ deg1,
                                               int* __restrict__ off1, int N){
  const int* deg = blockIdx.x ? deg1 : deg0;
  int*       off = blockIdx.x ? off1 : off0;
  __shared__ int part[1024];
  const int t = threadIdx.x;
  const int per = (N + 1023)/1024;
  const int start = t*per, end = min(start+per, N);
  int s = 0;
  for(int i = start; i < end; i++) s += deg[i];
  part[t] = s;
  __syncthreads();
  for(int d = 1; d < 1024; d <<= 1){
    int v = (t >= d) ? part[t-d] : 0;
    __syncthreads();
    part[t] += v;
    __syncthreads();
  }
  int run = (t == 0) ? 0 : part[t-1];
  for(int i = start; i < end; i++){ off[i] = run; run += deg[i]; }
  if(t == 1023) off[N] = run;
}

// ---------------- dinv from total degree ----------------
__global__ void kdinv2(const int* __restrict__ deg0, const int* __restrict__ deg1,
                       float* __restrict__ dinv, int N){
  int i = blockIdx.x*blockDim.x + threadIdx.x;
  if(i >= N) return;
  int d = deg0[i] + deg1[i];
  dinv[i] = (d > 1) ? (1.f/(float)d) : 0.f;   // deg==1 hyperedges dropped
}

// ---------------- counting-sort edges by u (= build sorted edge arrays) -------
__global__ void kperm(const int* __restrict__ ei0, const int* __restrict__ ei1,
                      const float* __restrict__ nimp, const int* __restrict__ off0,
                      int* __restrict__ cur0, int* __restrict__ eis0,
                      int* __restrict__ eis1, int* __restrict__ orig,
                      float* __restrict__ imp, int E){
  int e = blockIdx.x*blockDim.x + threadIdx.x;
  if(e >= E) return;
  int u = ei0[e], v = ei1[e];
  int pos = off0[u] + atomicAdd(&cur0[u], 1);
  eis0[pos] = u;
  eis1[pos] = v;
  orig[pos] = e;
  imp[pos]  = fminf(nimp[u], nimp[v]);
}

// ---------------- v-side incidence list (sorted edge ids) ----------------
__global__ void kfillv(const int* __restrict__ eis1, const int* __restrict__ off1,
                       int* __restrict__ cur1, int* __restrict__ list1, int E){
  int p = blockIdx.x*blockDim.x + threadIdx.x;
  if(p >= E) return;
  int v = eis1[p];
  list1[off1[v] + atomicAdd(&cur1[v], 1)] = p;
}

// ---------------- W -> fragment-ready layout (bf16) ----------------
template<int DIN>
__global__ void kprepw(const float* __restrict__ W, u16* __restrict__ wf){
  constexpr int NC = DIN/32;
  constexpr int SLOTS = 4*NC*64;
  int s = blockIdx.x*blockDim.x + threadIdx.x;
  if(s >= SLOTS) return;
  int lane = s & 63;
  int c    = (s >> 6) % NC;
  int tt   = s / (NC*64);
  int n  = tt*16 + (lane & 15);
  int k0 = c*32 + (lane >> 4)*8;
  #pragma unroll
  for(int j = 0; j < 8; j++)
    wf[(size_t)s*8 + j] = f2bf(W[(size_t)(k0 + j)*64 + n]);
}

// ---------------- layer 0: MFMA GEMM (edge_attr[orig]*imp @ W0) ---------------
__global__ __launch_bounds__(256) void kgemm0(const float* __restrict__ srcf,
                                              u16* __restrict__ buf,
                                              const u16* __restrict__ wf,
                                              const float* __restrict__ imp,
                                              const int* __restrict__ orig,
                                              int E){
  const int t    = threadIdx.x;
  const int wv   = t >> 6;
  const int lane = t & 63;
  const int quad = lane >> 4;
  const int l15  = lane & 15;
  const int row0 = blockIdx.x*64 + wv*16;
  if(row0 >= E) return;                      // E % 16 == 0

  bf16x8 bfr[4];
  #pragma unroll
  for(int i = 0; i < 4; i++)
    bfr[i] = *(const bf16x8*)(wf + ((size_t)i*64 + lane)*8);

  const int myrow = row0 + l15;
  const int oe = orig[myrow];
  const float* s = srcf + (size_t)oe*32 + quad*8;
  const float sc = imp[myrow];
  f32x4 v0 = *(const f32x4*)s;
  f32x4 v1 = *(const f32x4*)(s+4);
  bf16x8 afr;
  afr[0]=(short)f2bf(v0.x*sc); afr[1]=(short)f2bf(v0.y*sc);
  afr[2]=(short)f2bf(v0.z*sc); afr[3]=(short)f2bf(v0.w*sc);
  afr[4]=(short)f2bf(v1.x*sc); afr[5]=(short)f2bf(v1.y*sc);
  afr[6]=(short)f2bf(v1.z*sc); afr[7]=(short)f2bf(v1.w*sc);

  #pragma unroll
  for(int tt = 0; tt < 4; tt++){
    f32x4 a = {0.f,0.f,0.f,0.f};
    a = __builtin_amdgcn_mfma_f32_16x16x32_bf16(afr, bfr[tt], a, 0, 0, 0);
    const int n = tt*16 + l15;
    #pragma unroll
    for(int r = 0; r < 4; r++)
      buf[(size_t)(row0 + quad*4 + r)*64 + n] = f2bf(a[r]);
  }
}

// ---------------- aggregate: he[n] = contiguous u-run + random v-list ----------
__global__ __launch_bounds__(256) void kagg(const u16* __restrict__ buf,
                                            const int* __restrict__ off0,
                                            const int* __restrict__ off1,
                                            const int* __restrict__ list1,
                                            u16* __restrict__ heb, int N){
  const int t = threadIdx.x, wv = t >> 6, lane = t & 63;
  const int n = blockIdx.x*4 + wv;
  if(n >= N) return;
  float s = 0.f;
  // u-side: contiguous sorted positions (streaming)
  int j = off0[n], end = off0[n+1];
  for(; j + 3 < end; j += 4){
    float a0 = bf2f(buf[(size_t)(j+0)*64 + lane]);
    float a1 = bf2f(buf[(size_t)(j+1)*64 + lane]);
    float a2 = bf2f(buf[(size_t)(j+2)*64 + lane]);
    float a3 = bf2f(buf[(size_t)(j+3)*64 + lane]);
    s += a0 + a1 + a2 + a3;
  }
  for(; j < end; j++) s += bf2f(buf[(size_t)j*64 + lane]);
  // v-side: random list
  j = off1[n]; end = off1[n+1];
  for(; j + 3 < end; j += 4){
    int p0 = list1[j], p1 = list1[j+1], p2 = list1[j+2], p3 = list1[j+3];
    float a0 = bf2f(buf[(size_t)p0*64 + lane]);
    float a1 = bf2f(buf[(size_t)p1*64 + lane]);
    float a2 = bf2f(buf[(size_t)p2*64 + lane]);
    float a3 = bf2f(buf[(size_t)p3*64 + lane]);
    s += a0 + a1 + a2 + a3;
  }
  for(; j < end; j++) s += bf2f(buf[(size_t)list1[j]*64 + lane]);
  heb[(size_t)n*64 + lane] = f2bf(s);
}

// ---------------- fused: gather + epilogue + pool (+ next-layer GEMM) ----------
template<bool DO_GEMM>
__global__ __launch_bounds__(256) void kfused(u16* buf,               // r/w
                                              const u16* __restrict__ heb,
                                              const float* __restrict__ dinv,
                                              const int* __restrict__ eis0,
                                              const int* __restrict__ eis1,
                                              const float* __restrict__ imp,
                                              const float* __restrict__ bias,
                                              const int* __restrict__ batch,
                                              const u16* __restrict__ wf,
                                              float* __restrict__ ghL,  // gh + layer*64
                                              int E){
  __shared__ float ghl[4096];                       // 16 KB graph pool
  constexpr int HTSZ = DO_GEMM ? 4*16*72 : 4;       // 16 rows x 72 (16B-aligned)
  __shared__ __align__(16) u16 hT[HTSZ];
  const int t = threadIdx.x, wv = t >> 6, lane = t & 63;
  const int quad = lane >> 4, l15 = lane & 15;
  for(int i = t; i < 4096; i += 256) ghl[i] = 0.f;
  __syncthreads();
  const float bd = bias[lane];

  bf16x8 bfr[8];
  if(DO_GEMM){
    #pragma unroll
    for(int i = 0; i < 8; i++)
      bfr[i] = *(const bf16x8*)(wf + ((size_t)i*64 + lane)*8);
  }

  for(int base = blockIdx.x*64; base < E; base += gridDim.x*64){
    const int r0 = base + wv*16;
    if(r0 < E){                                   // E % 16 == 0
      // ---- stage 1: gather + epilogue, 2 groups of 8 edges (ILP-8) ----
      #pragma unroll
      for(int g = 0; g < 2; g++){
        const int e0 = r0 + g*8;
        int u8[8], v8[8], g8[8];
        float iu8[8], iv8[8], ie8[8], bv8[8], hu8[8], hv8[8];
        #pragma unroll
        for(int q = 0; q < 8; q++){ u8[q] = eis0[e0+q]; v8[q] = eis1[e0+q]; }
        #pragma unroll
        for(int q = 0; q < 8; q++){
          hv8[q] = bf2f(heb[(size_t)v8[q]*64 + lane]);   // random side first
          hu8[q] = bf2f(heb[(size_t)u8[q]*64 + lane]);   // monotone side (hot)
          bv8[q] = bf2f(buf[(size_t)(e0+q)*64 + lane]);
          iu8[q] = dinv[u8[q]];
          iv8[q] = dinv[v8[q]];
          ie8[q] = imp[e0+q];
          g8[q]  = batch[u8[q]];
        }
        #pragma unroll
        for(int q = 0; q < 8; q++){
          float val = bv8[q] + hu8[q]*iu8[q] + hv8[q]*iv8[q];
          float rc = (iu8[q] > 0.f && iv8[q] > 0.f) ? (1.f/3.f)
                   : ((iu8[q] > 0.f || iv8[q] > 0.f) ? 0.5f : 1.f);
          float o = fmaxf(val*rc + bd, 0.f) * ie8[q];
          atomicAdd(&ghl[g8[q]*64 + lane], o);
          if(DO_GEMM) hT[wv*1152 + (g*8+q)*72 + lane] = f2bf(o);
        }
      }
      // ---- stage 2: MFMA these 16 rows (wave-local LDS, no barrier) ----
      if(DO_GEMM){
        bf16x8 afr0 = *(const bf16x8*)&hT[wv*1152 + l15*72 + quad*8];
        bf16x8 afr1 = *(const bf16x8*)&hT[wv*1152 + l15*72 + 32 + quad*8];
        #pragma unroll
        for(int tt = 0; tt < 4; tt++){
          f32x4 a = {0.f,0.f,0.f,0.f};
          a = __builtin_amdgcn_mfma_f32_16x16x32_bf16(afr0, bfr[tt*2+0], a, 0, 0, 0);
          a = __builtin_amdgcn_mfma_f32_16x16x32_bf16(afr1, bfr[tt*2+1], a, 0, 0, 0);
          const int n = tt*16 + l15;
          #pragma unroll
          for(int r = 0; r < 4; r++)
            buf[(size_t)(r0 + quad*4 + r)*64 + n] = f2bf(a[r]);
        }
      }
    }
  }
  __syncthreads();
  for(int i = t; i < 4096; i += 256){
    float v = ghl[i];
    if(v != 0.f) atomAddF(&ghL[(i>>6)*192 + (i&63)], v);
  }
}

__global__ void kfinal(const float* __restrict__ gh, float* __restrict__ out, int n){
  int i = blockIdx.x*blockDim.x + threadIdx.x;
  if(i < n) out[i] = gh[i];   // reference output dtype = float32
}

// ---------------- host ----------------
extern "C" void kernel_launch(void* const* d_in, const int* in_sizes, int n_in,
                              void* d_out, int out_size, void* d_ws, size_t ws_size,
                              hipStream_t stream) {
  const float* edge_attr = (const float*)d_in[1];
  const int*   ei        = (const int*)d_in[2];
  const int*   batch     = (const int*)d_in[3];
  const float* nimp      = (const float*)d_in[4];
  const float* Ws[3] = { (const float*)d_in[5], (const float*)d_in[7], (const float*)d_in[9] };
  const float* bs[3] = { (const float*)d_in[6], (const float*)d_in[8], (const float*)d_in[10] };

  const int E = in_sizes[1] / 32;   // edge_attr is (E, 32)
  const int N = in_sizes[4];        // node_imp is (N,)
  const int* ei0 = ei;
  const int* ei1 = ei + E;

  char* p = (char*)d_ws;
  auto carve = [&](size_t bytes)->char*{
    char* r = p; p += (bytes + 255) & ~(size_t)255; return r;
  };
  float* imp   = (float*)carve((size_t)E*4);        // at sorted position
  int*   deg0  = (int*)  carve((size_t)4*N*4);      // deg0|deg1|cur0|cur1
  int*   deg1  = deg0 + N;
  int*   cur0  = deg0 + 2*N;
  int*   cur1  = deg0 + 3*N;
  float* dinv  = (float*)carve((size_t)N*4);
  int*   off0  = (int*)  carve((size_t)(N+1)*4);
  int*   off1  = (int*)  carve((size_t)(N+1)*4);
  int*   eis0  = (int*)  carve((size_t)E*4);
  int*   eis1  = (int*)  carve((size_t)E*4);
  int*   orig  = (int*)  carve((size_t)E*4);
  int*   list1 = (int*)  carve((size_t)E*4);
  u16*   heb   = (u16*)  carve((size_t)N*64*2);
  u16*   buf   = (u16*)  carve((size_t)E*64*2);     // xw / h' in-place
  float* gh    = (float*)carve((size_t)64*192*4);
  u16*   wfs[3];
  for(int l = 0; l < 3; l++) wfs[l] = (u16*)carve((size_t)4096*2);

  kzero<<<(4*N+255)/256, 256, 0, stream>>>(deg0, 4*N);
  kzero<<<(12288+255)/256, 256, 0, stream>>>((int*)gh, 12288);
  kdeg2<<<(E+255)/256, 256, 0, stream>>>(ei0, ei1, deg0, deg1, E);
  kscan2<<<2, 1024, 0, stream>>>(deg0, off0, deg1, off1, N);
  kdinv2<<<(N+255)/256, 256, 0, stream>>>(deg0, deg1, dinv, N);
  kperm<<<(E+255)/256, 256, 0, stream>>>(ei0, ei1, nimp, off0, cur0,
                                         eis0, eis1, orig, imp, E);
  kfillv<<<(E+255)/256, 256, 0, stream>>>(eis1, off1, cur1, list1, E);
  kprepw<32><<<1, 256, 0, stream>>>(Ws[0], wfs[0]);
  kprepw<64><<<2, 256, 0, stream>>>(Ws[1], wfs[1]);
  kprepw<64><<<2, 256, 0, stream>>>(Ws[2], wfs[2]);

  const int nbG  = (E + 63)/64;
  const int nbA  = (N + 3)/4;
  const int nbF  = 1536;   // 6 blocks/CU at ~25.6 KB LDS
  const int nbF3 = 2048;   // 8 blocks/CU at 16 KB LDS

  kgemm0<<<nbG, 256, 0, stream>>>(edge_attr, buf, wfs[0], imp, orig, E);
  kagg<<<nbA, 256, 0, stream>>>(buf, off0, off1, list1, heb, N);
  kfused<true ><<<nbF, 256, 0, stream>>>(buf, heb, dinv, eis0, eis1, imp, bs[0],
                                         batch, wfs[1], gh + 0*64, E);
  kagg<<<nbA, 256, 0, stream>>>(buf, off0, off1, list1, heb, N);
  kfused<true ><<<nbF, 256, 0, stream>>>(buf, heb, dinv, eis0, eis1, imp, bs[1],
                                         batch, wfs[2], gh + 1*64, E);
  kagg<<<nbA, 256, 0, stream>>>(buf, off0, off1, list1, heb, N);
  kfused<false><<<nbF3, 256, 0, stream>>>(buf, heb, dinv, eis0, eis1, imp, bs[2],
                                          batch, nullptr, gh + 2*64, E);
  kfinal<<<(12288+255)/256, 256, 0, stream>>>(gh, (float*)d_out, 12288);
}

// Round 9
// 598.522 us; speedup vs baseline: 2.6704x; 1.6081x over previous
//
#include <hip/hip_runtime.h>
#include <hip/hip_bf16.h>
#include <cstdint>
#include <cstddef>

typedef unsigned short u16;
typedef unsigned int   u32;
typedef short bf16x8 __attribute__((ext_vector_type(8)));   // 8 bf16 = 4 VGPRs
typedef float f32x4  __attribute__((ext_vector_type(4)));

__device__ __forceinline__ float bf2f(u16 v){ return __uint_as_float(((u32)v)<<16); }
__device__ __forceinline__ u16 f2bf(float f){
  u32 x = __float_as_uint(f);
  return (u16)((x + 0x7FFFu + ((x>>16)&1u)) >> 16);   // round-to-nearest-even
}
__device__ __forceinline__ void atomAddF(float* p, float v){ unsafeAtomicAdd(p, v); }

// ---------------- zero helper ----------------
__global__ void kzero(int* p, int n){
  int i = blockIdx.x*blockDim.x + threadIdx.x;
  if(i < n) p[i] = 0;
}

// ---------------- per-side degree counts ----------------
__global__ void kdeg2(const int* __restrict__ ei0, const int* __restrict__ ei1,
                      int* __restrict__ deg0, int* __restrict__ deg1, int E){
  int e = blockIdx.x*blockDim.x + threadIdx.x;
  if(e >= E) return;
  atomicAdd(&deg0[ei0[e]], 1);
  atomicAdd(&deg1[ei1[e]], 1);
}

// ---------------- dual exclusive prefix scan (block 0: deg0, block 1: deg1) ----
__global__ __launch_bounds__(1024) void kscan2(const int* __restrict__ deg0,
                                               int* __restrict__ off0,
                                               const int* __restrict__ deg1,
                                               int* __restrict__ off1, int N){
  const int* deg = blockIdx.x ? deg1 : deg0;
  int*       off = blockIdx.x ? off1 : off0;
  __shared__ int part[1024];
  const int t = threadIdx.x;
  const int per = (N + 1023)/1024;
  const int start = t*per, end = min(start+per, N);
  int s = 0;
  for(int i = start; i < end; i++) s += deg[i];
  part[t] = s;
  __syncthreads();
  for(int d = 1; d < 1024; d <<= 1){
    int v = (t >= d) ? part[t-d] : 0;
    __syncthreads();
    part[t] += v;
    __syncthreads();
  }
  int run = (t == 0) ? 0 : part[t-1];
  for(int i = start; i < end; i++){ off[i] = run; run += deg[i]; }
  if(t == 1023) off[N] = run;
}

// ---------------- dinv from total degree ----------------
__global__ void kdinv2(const int* __restrict__ deg0, const int* __restrict__ deg1,
                       float* __restrict__ dinv, int N){
  int i = blockIdx.x*blockDim.x + threadIdx.x;
  if(i >= N) return;
  int d = deg0[i] + deg1[i];
  dinv[i] = (d > 1) ? (1.f/(float)d) : 0.f;   // deg==1 hyperedges dropped
}

// ---------------- counting-sort edges by u ----------------
__global__ void kperm(const int* __restrict__ ei0, const int* __restrict__ ei1,
                      const float* __restrict__ nimp, const int* __restrict__ off0,
                      int* __restrict__ cur0, int* __restrict__ eis0,
                      int* __restrict__ eis1, int* __restrict__ orig,
                      float* __restrict__ imp, int E){
  int e = blockIdx.x*blockDim.x + threadIdx.x;
  if(e >= E) return;
  int u = ei0[e], v = ei1[e];
  int pos = off0[u] + atomicAdd(&cur0[u], 1);
  eis0[pos] = u;
  eis1[pos] = v;
  orig[pos] = e;
  imp[pos]  = fminf(nimp[u], nimp[v]);
}

// ---------------- v-side incidence list (sorted edge ids) ----------------
__global__ void kfillv(const int* __restrict__ eis1, const int* __restrict__ off1,
                       int* __restrict__ cur1, int* __restrict__ list1, int E){
  int p = blockIdx.x*blockDim.x + threadIdx.x;
  if(p >= E) return;
  int v = eis1[p];
  list1[off1[v] + atomicAdd(&cur1[v], 1)] = p;
}

// ---------------- W -> fragment-ready layout (bf16) ----------------
template<int DIN>
__global__ void kprepw(const float* __restrict__ W, u16* __restrict__ wf){
  constexpr int NC = DIN/32;
  constexpr int SLOTS = 4*NC*64;
  int s = blockIdx.x*blockDim.x + threadIdx.x;
  if(s >= SLOTS) return;
  int lane = s & 63;
  int c    = (s >> 6) % NC;
  int tt   = s / (NC*64);
  int n  = tt*16 + (lane & 15);
  int k0 = c*32 + (lane >> 4)*8;
  #pragma unroll
  for(int j = 0; j < 8; j++)
    wf[(size_t)s*8 + j] = f2bf(W[(size_t)(k0 + j)*64 + n]);
}

// ---------------- layer 0: MFMA GEMM (edge_attr[orig]*imp @ W0) ---------------
__global__ __launch_bounds__(256) void kgemm0(const float* __restrict__ srcf,
                                              u16* __restrict__ buf,
                                              const u16* __restrict__ wf,
                                              const float* __restrict__ imp,
                                              const int* __restrict__ orig,
                                              int E){
  const int t    = threadIdx.x;
  const int wv   = t >> 6;
  const int lane = t & 63;
  const int quad = lane >> 4;
  const int l15  = lane & 15;
  const int row0 = blockIdx.x*64 + wv*16;
  if(row0 >= E) return;                      // E % 16 == 0

  bf16x8 bfr[4];
  #pragma unroll
  for(int i = 0; i < 4; i++)
    bfr[i] = *(const bf16x8*)(wf + ((size_t)i*64 + lane)*8);

  const int myrow = row0 + l15;
  const int oe = orig[myrow];
  const float* s = srcf + (size_t)oe*32 + quad*8;
  const float sc = imp[myrow];
  f32x4 v0 = *(const f32x4*)s;
  f32x4 v1 = *(const f32x4*)(s+4);
  bf16x8 afr;
  afr[0]=(short)f2bf(v0.x*sc); afr[1]=(short)f2bf(v0.y*sc);
  afr[2]=(short)f2bf(v0.z*sc); afr[3]=(short)f2bf(v0.w*sc);
  afr[4]=(short)f2bf(v1.x*sc); afr[5]=(short)f2bf(v1.y*sc);
  afr[6]=(short)f2bf(v1.z*sc); afr[7]=(short)f2bf(v1.w*sc);

  #pragma unroll
  for(int tt = 0; tt < 4; tt++){
    f32x4 a = {0.f,0.f,0.f,0.f};
    a = __builtin_amdgcn_mfma_f32_16x16x32_bf16(afr, bfr[tt], a, 0, 0, 0);
    const int n = tt*16 + l15;
    #pragma unroll
    for(int r = 0; r < 4; r++)
      buf[(size_t)(row0 + quad*4 + r)*64 + n] = f2bf(a[r]);
  }
}

// ---------------- aggregate: he[n] = contiguous u-run + random v-list ----------
__global__ __launch_bounds__(256) void kagg(const u16* __restrict__ buf,
                                            const int* __restrict__ off0,
                                            const int* __restrict__ off1,
                                            const int* __restrict__ list1,
                                            u16* __restrict__ heb, int N){
  const int t = threadIdx.x, wv = t >> 6, lane = t & 63;
  const int n = blockIdx.x*4 + wv;
  if(n >= N) return;
  float s = 0.f;
  // u-side: contiguous sorted positions (streaming)
  int j = off0[n], end = off0[n+1];
  for(; j + 3 < end; j += 4){
    float a0 = bf2f(buf[(size_t)(j+0)*64 + lane]);
    float a1 = bf2f(buf[(size_t)(j+1)*64 + lane]);
    float a2 = bf2f(buf[(size_t)(j+2)*64 + lane]);
    float a3 = bf2f(buf[(size_t)(j+3)*64 + lane]);
    s += a0 + a1 + a2 + a3;
  }
  for(; j < end; j++) s += bf2f(buf[(size_t)j*64 + lane]);
  // v-side: random list
  j = off1[n]; end = off1[n+1];
  for(; j + 3 < end; j += 4){
    int p0 = list1[j], p1 = list1[j+1], p2 = list1[j+2], p3 = list1[j+3];
    float a0 = bf2f(buf[(size_t)p0*64 + lane]);
    float a1 = bf2f(buf[(size_t)p1*64 + lane]);
    float a2 = bf2f(buf[(size_t)p2*64 + lane]);
    float a3 = bf2f(buf[(size_t)p3*64 + lane]);
    s += a0 + a1 + a2 + a3;
  }
  for(; j < end; j++) s += bf2f(buf[(size_t)list1[j]*64 + lane]);
  heb[(size_t)n*64 + lane] = f2bf(s);
}

// ---------------- fused: gather + epilogue + register-pool (+ GEMM) ------------
// Contiguous chunk per block (CH=256 edges, 4 iters x 64). batch monotone in
// sorted-edge order -> per-lane register pooling with rare coalesced flushes.
template<bool DO_GEMM>
__global__ __launch_bounds__(256) void kfused(u16* buf,               // r/w
                                              const u16* __restrict__ heb,
                                              const float* __restrict__ dinv,
                                              const int* __restrict__ eis0,
                                              const int* __restrict__ eis1,
                                              const float* __restrict__ imp,
                                              const float* __restrict__ bias,
                                              const int* __restrict__ batch,
                                              const u16* __restrict__ wf,
                                              float* __restrict__ ghL,  // gh + layer*64
                                              int E){
  constexpr int HTSZ = DO_GEMM ? 4*16*72 : 4;       // 16 rows x 72 per wave
  __shared__ __align__(16) u16 hT[HTSZ];
  const int t = threadIdx.x, wv = t >> 6, lane = t & 63;
  const int quad = lane >> 4, l15 = lane & 15;
  const float bd = bias[lane];

  bf16x8 bfr[8];
  if(DO_GEMM){
    #pragma unroll
    for(int i = 0; i < 8; i++)
      bfr[i] = *(const bf16x8*)(wf + ((size_t)i*64 + lane)*8);
  }

  float pool = 0.f;
  int cur_g = -1;

  const int chunk0 = blockIdx.x*256;
  #pragma unroll 1
  for(int it = 0; it < 4; it++){
    const int r0 = chunk0 + it*64 + wv*16;
    if(r0 < E){                                   // E % 16 == 0
      // ---- stage 1: gather + epilogue, 2 groups of 8 edges (ILP-8) ----
      #pragma unroll
      for(int g = 0; g < 2; g++){
        const int e0 = r0 + g*8;
        int u8[8], v8[8], g8[8];
        float iu8[8], iv8[8], ie8[8], bv8[8], hu8[8], hv8[8];
        #pragma unroll
        for(int q = 0; q < 8; q++){ u8[q] = eis0[e0+q]; v8[q] = eis1[e0+q]; }
        #pragma unroll
        for(int q = 0; q < 8; q++){
          hv8[q] = bf2f(heb[(size_t)v8[q]*64 + lane]);   // random side first
          hu8[q] = bf2f(heb[(size_t)u8[q]*64 + lane]);   // monotone side (hot)
          bv8[q] = bf2f(buf[(size_t)(e0+q)*64 + lane]);
          iu8[q] = dinv[u8[q]];
          iv8[q] = dinv[v8[q]];
          ie8[q] = imp[e0+q];
          g8[q]  = batch[u8[q]];                         // wave-uniform, monotone
        }
        #pragma unroll
        for(int q = 0; q < 8; q++){
          float val = bv8[q] + hu8[q]*iu8[q] + hv8[q]*iv8[q];
          float rc = (iu8[q] > 0.f && iv8[q] > 0.f) ? (1.f/3.f)
                   : ((iu8[q] > 0.f || iv8[q] > 0.f) ? 0.5f : 1.f);
          float o = fmaxf(val*rc + bd, 0.f) * ie8[q];
          if(g8[q] != cur_g){                            // wave-uniform branch
            if(cur_g >= 0) atomAddF(&ghL[cur_g*192 + lane], pool);
            pool = 0.f;
            cur_g = g8[q];
          }
          pool += o;
          if(DO_GEMM) hT[wv*1152 + (g*8+q)*72 + lane] = f2bf(o);
        }
      }
      // ---- stage 2: MFMA these 16 rows (wave-local LDS, no barrier) ----
      if(DO_GEMM){
        bf16x8 afr0 = *(const bf16x8*)&hT[wv*1152 + l15*72 + quad*8];
        bf16x8 afr1 = *(const bf16x8*)&hT[wv*1152 + l15*72 + 32 + quad*8];
        #pragma unroll
        for(int tt = 0; tt < 4; tt++){
          f32x4 a = {0.f,0.f,0.f,0.f};
          a = __builtin_amdgcn_mfma_f32_16x16x32_bf16(afr0, bfr[tt*2+0], a, 0, 0, 0);
          a = __builtin_amdgcn_mfma_f32_16x16x32_bf16(afr1, bfr[tt*2+1], a, 0, 0, 0);
          const int n = tt*16 + l15;
          #pragma unroll
          for(int r = 0; r < 4; r++)
            buf[(size_t)(r0 + quad*4 + r)*64 + n] = f2bf(a[r]);
        }
      }
    }
  }
  if(cur_g >= 0) atomAddF(&ghL[cur_g*192 + lane], pool);
}

__global__ void kfinal(const float* __restrict__ gh, float* __restrict__ out, int n){
  int i = blockIdx.x*blockDim.x + threadIdx.x;
  if(i < n) out[i] = gh[i];   // reference output dtype = float32
}

// ---------------- host ----------------
extern "C" void kernel_launch(void* const* d_in, const int* in_sizes, int n_in,
                              void* d_out, int out_size, void* d_ws, size_t ws_size,
                              hipStream_t stream) {
  const float* edge_attr = (const float*)d_in[1];
  const int*   ei        = (const int*)d_in[2];
  const int*   batch     = (const int*)d_in[3];
  const float* nimp      = (const float*)d_in[4];
  const float* Ws[3] = { (const float*)d_in[5], (const float*)d_in[7], (const float*)d_in[9] };
  const float* bs[3] = { (const float*)d_in[6], (const float*)d_in[8], (const float*)d_in[10] };

  const int E = in_sizes[1] / 32;   // edge_attr is (E, 32)
  const int N = in_sizes[4];        // node_imp is (N,)
  const int* ei0 = ei;
  const int* ei1 = ei + E;

  char* p = (char*)d_ws;
  auto carve = [&](size_t bytes)->char*{
    char* r = p; p += (bytes + 255) & ~(size_t)255; return r;
  };
  float* imp   = (float*)carve((size_t)E*4);        // at sorted position
  int*   deg0  = (int*)  carve((size_t)4*N*4);      // deg0|deg1|cur0|cur1
  int*   deg1  = deg0 + N;
  int*   cur0  = deg0 + 2*N;
  int*   cur1  = deg0 + 3*N;
  float* dinv  = (float*)carve((size_t)N*4);
  int*   off0  = (int*)  carve((size_t)(N+1)*4);
  int*   off1  = (int*)  carve((size_t)(N+1)*4);
  int*   eis0  = (int*)  carve((size_t)E*4);
  int*   eis1  = (int*)  carve((size_t)E*4);
  int*   orig  = (int*)  carve((size_t)E*4);
  int*   list1 = (int*)  carve((size_t)E*4);
  u16*   heb   = (u16*)  carve((size_t)N*64*2);
  u16*   buf   = (u16*)  carve((size_t)E*64*2);     // xw / h' in-place
  float* gh    = (float*)carve((size_t)64*192*4);
  u16*   wfs[3];
  for(int l = 0; l < 3; l++) wfs[l] = (u16*)carve((size_t)4096*2);

  kzero<<<(4*N+255)/256, 256, 0, stream>>>(deg0, 4*N);
  kzero<<<(12288+255)/256, 256, 0, stream>>>((int*)gh, 12288);
  kdeg2<<<(E+255)/256, 256, 0, stream>>>(ei0, ei1, deg0, deg1, E);
  kscan2<<<2, 1024, 0, stream>>>(deg0, off0, deg1, off1, N);
  kdinv2<<<(N+255)/256, 256, 0, stream>>>(deg0, deg1, dinv, N);
  kperm<<<(E+255)/256, 256, 0, stream>>>(ei0, ei1, nimp, off0, cur0,
                                         eis0, eis1, orig, imp, E);
  kfillv<<<(E+255)/256, 256, 0, stream>>>(eis1, off1, cur1, list1, E);
  kprepw<32><<<1, 256, 0, stream>>>(Ws[0], wfs[0]);
  kprepw<64><<<2, 256, 0, stream>>>(Ws[1], wfs[1]);
  kprepw<64><<<2, 256, 0, stream>>>(Ws[2], wfs[2]);

  const int nbG = (E + 63)/64;
  const int nbA = (N + 3)/4;
  const int nbF = (E + 255)/256;   // contiguous 256-edge chunk per block

  kgemm0<<<nbG, 256, 0, stream>>>(edge_attr, buf, wfs[0], imp, orig, E);
  kagg<<<nbA, 256, 0, stream>>>(buf, off0, off1, list1, heb, N);
  kfused<true ><<<nbF, 256, 0, stream>>>(buf, heb, dinv, eis0, eis1, imp, bs[0],
                                         batch, wfs[1], gh + 0*64, E);
  kagg<<<nbA, 256, 0, stream>>>(buf, off0, off1, list1, heb, N);
  kfused<true ><<<nbF, 256, 0, stream>>>(buf, heb, dinv, eis0, eis1, imp, bs[1],
                                         batch, wfs[2], gh + 1*64, E);
  kagg<<<nbA, 256, 0, stream>>>(buf, off0, off1, list1, heb, N);
  kfused<false><<<nbF, 256, 0, stream>>>(buf, heb, dinv, eis0, eis1, imp, bs[2],
                                         batch, nullptr, gh + 2*64, E);
  kfinal<<<(12288+255)/256, 256, 0, stream>>>(gh, (float*)d_out, 12288);
}

// Round 10
// 529.375 us; speedup vs baseline: 3.0192x; 1.1306x over previous
//
#include <hip/hip_runtime.h>
#include <hip/hip_bf16.h>
#include <cstdint>
#include <cstddef>

typedef unsigned short u16;
typedef unsigned int   u32;
typedef short bf16x8 __attribute__((ext_vector_type(8)));   // 8 bf16 = 4 VGPRs
typedef float f32x4  __attribute__((ext_vector_type(4)));

__device__ __forceinline__ float bf2f(u16 v){ return __uint_as_float(((u32)v)<<16); }
__device__ __forceinline__ u16 f2bf(float f){
  u32 x = __float_as_uint(f);
  return (u16)((x + 0x7FFFu + ((x>>16)&1u)) >> 16);   // round-to-nearest-even
}
__device__ __forceinline__ void atomAddF(float* p, float v){ unsafeAtomicAdd(p, v); }

// ---------------- zero helper ----------------
__global__ void kzero(int* p, int n){
  int i = blockIdx.x*blockDim.x + threadIdx.x;
  if(i < n) p[i] = 0;
}

// ---------------- per-side degree counts ----------------
__global__ void kdeg2(const int* __restrict__ ei0, const int* __restrict__ ei1,
                      int* __restrict__ deg0, int* __restrict__ deg1, int E){
  int e = blockIdx.x*blockDim.x + threadIdx.x;
  if(e >= E) return;
  atomicAdd(&deg0[ei0[e]], 1);
  atomicAdd(&deg1[ei1[e]], 1);
}

// ---------------- hierarchical exclusive scan (3 phases, fully parallel) -------
// phase 1: per-256-tile sums for deg0 (blocks 0..nt-1) and deg1 (nt..2nt-1)
__global__ __launch_bounds__(256) void ktilesum(const int* __restrict__ deg0,
                                                const int* __restrict__ deg1,
                                                int* __restrict__ tsum,
                                                int N, int nt){
  __shared__ int sh[256];
  const int b = blockIdx.x;
  const int* deg = (b < nt) ? deg0 : deg1;
  const int tile = (b < nt) ? b : b - nt;
  const int t = threadIdx.x;
  const int i = tile*256 + t;
  sh[t] = (i < N) ? deg[i] : 0;
  __syncthreads();
  for(int s = 128; s > 0; s >>= 1){
    if(t < s) sh[t] += sh[t+s];
    __syncthreads();
  }
  if(t == 0) tsum[b] = sh[0];
}
// phase 2: scan tile sums (block 0: array0, block 1: array1); writes off[N]
__global__ __launch_bounds__(256) void kmid(int* __restrict__ tsum,
                                            int* __restrict__ off0,
                                            int* __restrict__ off1,
                                            int N, int nt){
  __shared__ int sh[256];
  const int b = blockIdx.x;
  int* ts = tsum + b*nt;
  const int t = threadIdx.x;
  sh[t] = (t < nt) ? ts[t] : 0;
  __syncthreads();
  for(int s = 1; s < 256; s <<= 1){
    int x = (t >= s) ? sh[t-s] : 0;
    __syncthreads();
    sh[t] += x;
    __syncthreads();
  }
  if(t < nt) ts[t] = (t == 0) ? 0 : sh[t-1];
  if(t == 255){ int* off = b ? off1 : off0; off[N] = sh[255]; }
}
// phase 3: intra-tile exclusive scan + tile base -> off[]
__global__ __launch_bounds__(256) void kapply(const int* __restrict__ deg0,
                                              const int* __restrict__ deg1,
                                              const int* __restrict__ tsum,
                                              int* __restrict__ off0,
                                              int* __restrict__ off1,
                                              int N, int nt){
  __shared__ int sh[256];
  const int b = blockIdx.x;
  const int* deg = (b < nt) ? deg0 : deg1;
  int*       off = (b < nt) ? off0 : off1;
  const int tile = (b < nt) ? b : b - nt;
  const int base = tsum[b];
  const int t = threadIdx.x;
  const int i = tile*256 + t;
  sh[t] = (i < N) ? deg[i] : 0;
  __syncthreads();
  for(int s = 1; s < 256; s <<= 1){
    int x = (t >= s) ? sh[t-s] : 0;
    __syncthreads();
    sh[t] += x;
    __syncthreads();
  }
  if(i < N) off[i] = base + ((t == 0) ? 0 : sh[t-1]);
}

// ---------------- dinv from total degree ----------------
__global__ void kdinv2(const int* __restrict__ deg0, const int* __restrict__ deg1,
                       float* __restrict__ dinv, int N){
  int i = blockIdx.x*blockDim.x + threadIdx.x;
  if(i >= N) return;
  int d = deg0[i] + deg1[i];
  dinv[i] = (d > 1) ? (1.f/(float)d) : 0.f;   // deg==1 hyperedges dropped
}

// ---------------- counting-sort edges by u ----------------
__global__ void kperm(const int* __restrict__ ei0, const int* __restrict__ ei1,
                      const float* __restrict__ nimp, const int* __restrict__ off0,
                      int* __restrict__ cur0, int* __restrict__ eis0,
                      int* __restrict__ eis1, int* __restrict__ orig,
                      float* __restrict__ imp, int E){
  int e = blockIdx.x*blockDim.x + threadIdx.x;
  if(e >= E) return;
  int u = ei0[e], v = ei1[e];
  int pos = off0[u] + atomicAdd(&cur0[u], 1);
  eis0[pos] = u;
  eis1[pos] = v;
  orig[pos] = e;
  imp[pos]  = fminf(nimp[u], nimp[v]);
}

// ---------------- v-side incidence list (sorted edge ids) ----------------
__global__ void kfillv(const int* __restrict__ eis1, const int* __restrict__ off1,
                       int* __restrict__ cur1, int* __restrict__ list1, int E){
  int p = blockIdx.x*blockDim.x + threadIdx.x;
  if(p >= E) return;
  int v = eis1[p];
  list1[off1[v] + atomicAdd(&cur1[v], 1)] = p;
}

// ---------------- W -> fragment-ready layout (bf16) ----------------
template<int DIN>
__global__ void kprepw(const float* __restrict__ W, u16* __restrict__ wf){
  constexpr int NC = DIN/32;
  constexpr int SLOTS = 4*NC*64;
  int s = blockIdx.x*blockDim.x + threadIdx.x;
  if(s >= SLOTS) return;
  int lane = s & 63;
  int c    = (s >> 6) % NC;
  int tt   = s / (NC*64);
  int n  = tt*16 + (lane & 15);
  int k0 = c*32 + (lane >> 4)*8;
  #pragma unroll
  for(int j = 0; j < 8; j++)
    wf[(size_t)s*8 + j] = f2bf(W[(size_t)(k0 + j)*64 + n]);
}

// ---------------- layer 0: MFMA GEMM (edge_attr[orig]*imp @ W0) ---------------
__global__ __launch_bounds__(256) void kgemm0(const float* __restrict__ srcf,
                                              u16* __restrict__ buf,
                                              const u16* __restrict__ wf,
                                              const float* __restrict__ imp,
                                              const int* __restrict__ orig,
                                              int E){
  const int t    = threadIdx.x;
  const int wv   = t >> 6;
  const int lane = t & 63;
  const int quad = lane >> 4;
  const int l15  = lane & 15;
  const int row0 = blockIdx.x*64 + wv*16;
  if(row0 >= E) return;                      // E % 16 == 0

  bf16x8 bfr[4];
  #pragma unroll
  for(int i = 0; i < 4; i++)
    bfr[i] = *(const bf16x8*)(wf + ((size_t)i*64 + lane)*8);

  const int myrow = row0 + l15;
  const int oe = orig[myrow];
  const float* s = srcf + (size_t)oe*32 + quad*8;
  const float sc = imp[myrow];
  f32x4 v0 = *(const f32x4*)s;
  f32x4 v1 = *(const f32x4*)(s+4);
  bf16x8 afr;
  afr[0]=(short)f2bf(v0.x*sc); afr[1]=(short)f2bf(v0.y*sc);
  afr[2]=(short)f2bf(v0.z*sc); afr[3]=(short)f2bf(v0.w*sc);
  afr[4]=(short)f2bf(v1.x*sc); afr[5]=(short)f2bf(v1.y*sc);
  afr[6]=(short)f2bf(v1.z*sc); afr[7]=(short)f2bf(v1.w*sc);

  #pragma unroll
  for(int tt = 0; tt < 4; tt++){
    f32x4 a = {0.f,0.f,0.f,0.f};
    a = __builtin_amdgcn_mfma_f32_16x16x32_bf16(afr, bfr[tt], a, 0, 0, 0);
    const int n = tt*16 + l15;
    #pragma unroll
    for(int r = 0; r < 4; r++)
      buf[(size_t)(row0 + quad*4 + r)*64 + n] = f2bf(a[r]);
  }
}

// ---------------- aggregate: he[n] = contiguous u-run + random v-list ----------
__global__ __launch_bounds__(256) void kagg(const u16* __restrict__ buf,
                                            const int* __restrict__ off0,
                                            const int* __restrict__ off1,
                                            const int* __restrict__ list1,
                                            u16* __restrict__ heb, int N){
  const int t = threadIdx.x, wv = t >> 6, lane = t & 63;
  const int n = blockIdx.x*4 + wv;
  if(n >= N) return;
  float s = 0.f;
  // u-side: contiguous sorted positions (streaming)
  int j = off0[n], end = off0[n+1];
  for(; j + 3 < end; j += 4){
    float a0 = bf2f(buf[(size_t)(j+0)*64 + lane]);
    float a1 = bf2f(buf[(size_t)(j+1)*64 + lane]);
    float a2 = bf2f(buf[(size_t)(j+2)*64 + lane]);
    float a3 = bf2f(buf[(size_t)(j+3)*64 + lane]);
    s += a0 + a1 + a2 + a3;
  }
  for(; j < end; j++) s += bf2f(buf[(size_t)j*64 + lane]);
  // v-side: random list
  j = off1[n]; end = off1[n+1];
  for(; j + 3 < end; j += 4){
    int p0 = list1[j], p1 = list1[j+1], p2 = list1[j+2], p3 = list1[j+3];
    float a0 = bf2f(buf[(size_t)p0*64 + lane]);
    float a1 = bf2f(buf[(size_t)p1*64 + lane]);
    float a2 = bf2f(buf[(size_t)p2*64 + lane]);
    float a3 = bf2f(buf[(size_t)p3*64 + lane]);
    s += a0 + a1 + a2 + a3;
  }
  for(; j < end; j++) s += bf2f(buf[(size_t)list1[j]*64 + lane]);
  heb[(size_t)n*64 + lane] = f2bf(s);
}

// ---------------- fused: gather + epilogue + register-pool (+ GEMM) ------------
template<bool DO_GEMM>
__global__ __launch_bounds__(256) void kfused(u16* buf,               // r/w
                                              const u16* __restrict__ heb,
                                              const float* __restrict__ dinv,
                                              const int* __restrict__ eis0,
                                              const int* __restrict__ eis1,
                                              const float* __restrict__ imp,
                                              const float* __restrict__ bias,
                                              const int* __restrict__ batch,
                                              const u16* __restrict__ wf,
                                              float* __restrict__ ghL,  // gh + layer*64
                                              int E){
  constexpr int HTSZ = DO_GEMM ? 4*16*72 : 4;       // 16 rows x 72 per wave
  __shared__ __align__(16) u16 hT[HTSZ];
  const int t = threadIdx.x, wv = t >> 6, lane = t & 63;
  const int quad = lane >> 4, l15 = lane & 15;
  const float bd = bias[lane];

  bf16x8 bfr[8];
  if(DO_GEMM){
    #pragma unroll
    for(int i = 0; i < 8; i++)
      bfr[i] = *(const bf16x8*)(wf + ((size_t)i*64 + lane)*8);
  }

  float pool = 0.f;
  int cur_g = -1;

  const int chunk0 = blockIdx.x*256;
  #pragma unroll 1
  for(int it = 0; it < 4; it++){
    const int r0 = chunk0 + it*64 + wv*16;
    if(r0 < E){                                   // E % 16 == 0
      // ---- stage 1: gather + epilogue, 2 groups of 8 edges (ILP-8) ----
      #pragma unroll
      for(int g = 0; g < 2; g++){
        const int e0 = r0 + g*8;
        int u8[8], v8[8], g8[8];
        float iu8[8], iv8[8], ie8[8], bv8[8], hu8[8], hv8[8];
        #pragma unroll
        for(int q = 0; q < 8; q++){ u8[q] = eis0[e0+q]; v8[q] = eis1[e0+q]; }
        #pragma unroll
        for(int q = 0; q < 8; q++){
          hv8[q] = bf2f(heb[(size_t)v8[q]*64 + lane]);   // random side first
          hu8[q] = bf2f(heb[(size_t)u8[q]*64 + lane]);   // monotone side (hot)
          bv8[q] = bf2f(buf[(size_t)(e0+q)*64 + lane]);
          iu8[q] = dinv[u8[q]];
          iv8[q] = dinv[v8[q]];
          ie8[q] = imp[e0+q];
          g8[q]  = batch[u8[q]];                         // wave-uniform, monotone
        }
        #pragma unroll
        for(int q = 0; q < 8; q++){
          float val = bv8[q] + hu8[q]*iu8[q] + hv8[q]*iv8[q];
          float rc = (iu8[q] > 0.f && iv8[q] > 0.f) ? (1.f/3.f)
                   : ((iu8[q] > 0.f || iv8[q] > 0.f) ? 0.5f : 1.f);
          float o = fmaxf(val*rc + bd, 0.f) * ie8[q];
          if(g8[q] != cur_g){                            // wave-uniform branch
            if(cur_g >= 0) atomAddF(&ghL[cur_g*192 + lane], pool);
            pool = 0.f;
            cur_g = g8[q];
          }
          pool += o;
          if(DO_GEMM) hT[wv*1152 + (g*8+q)*72 + lane] = f2bf(o);
        }
      }
      // ---- stage 2: MFMA these 16 rows (wave-local LDS, no barrier) ----
      if(DO_GEMM){
        bf16x8 afr0 = *(const bf16x8*)&hT[wv*1152 + l15*72 + quad*8];
        bf16x8 afr1 = *(const bf16x8*)&hT[wv*1152 + l15*72 + 32 + quad*8];
        #pragma unroll
        for(int tt = 0; tt < 4; tt++){
          f32x4 a = {0.f,0.f,0.f,0.f};
          a = __builtin_amdgcn_mfma_f32_16x16x32_bf16(afr0, bfr[tt*2+0], a, 0, 0, 0);
          a = __builtin_amdgcn_mfma_f32_16x16x32_bf16(afr1, bfr[tt*2+1], a, 0, 0, 0);
          const int n = tt*16 + l15;
          #pragma unroll
          for(int r = 0; r < 4; r++)
            buf[(size_t)(r0 + quad*4 + r)*64 + n] = f2bf(a[r]);
        }
      }
    }
  }
  if(cur_g >= 0) atomAddF(&ghL[cur_g*192 + lane], pool);
}

__global__ void kfinal(const float* __restrict__ gh, float* __restrict__ out, int n){
  int i = blockIdx.x*blockDim.x + threadIdx.x;
  if(i < n) out[i] = gh[i];   // reference output dtype = float32
}

// ---------------- host ----------------
extern "C" void kernel_launch(void* const* d_in, const int* in_sizes, int n_in,
                              void* d_out, int out_size, void* d_ws, size_t ws_size,
                              hipStream_t stream) {
  const float* edge_attr = (const float*)d_in[1];
  const int*   ei        = (const int*)d_in[2];
  const int*   batch     = (const int*)d_in[3];
  const float* nimp      = (const float*)d_in[4];
  const float* Ws[3] = { (const float*)d_in[5], (const float*)d_in[7], (const float*)d_in[9] };
  const float* bs[3] = { (const float*)d_in[6], (const float*)d_in[8], (const float*)d_in[10] };

  const int E = in_sizes[1] / 32;   // edge_attr is (E, 32)
  const int N = in_sizes[4];        // node_imp is (N,)
  const int* ei0 = ei;
  const int* ei1 = ei + E;

  char* p = (char*)d_ws;
  auto carve = [&](size_t bytes)->char*{
    char* r = p; p += (bytes + 255) & ~(size_t)255; return r;
  };
  const int nt = (N + 255)/256;                      // scan tiles per array
  float* imp   = (float*)carve((size_t)E*4);         // at sorted position
  int*   deg0  = (int*)  carve((size_t)4*N*4);       // deg0|deg1|cur0|cur1
  int*   deg1  = deg0 + N;
  int*   cur0  = deg0 + 2*N;
  int*   cur1  = deg0 + 3*N;
  float* dinv  = (float*)carve((size_t)N*4);
  int*   off0  = (int*)  carve((size_t)(N+1)*4);
  int*   off1  = (int*)  carve((size_t)(N+1)*4);
  int*   tsum  = (int*)  carve((size_t)2*nt*4);
  int*   eis0  = (int*)  carve((size_t)E*4);
  int*   eis1  = (int*)  carve((size_t)E*4);
  int*   orig  = (int*)  carve((size_t)E*4);
  int*   list1 = (int*)  carve((size_t)E*4);
  u16*   heb   = (u16*)  carve((size_t)N*64*2);
  u16*   buf   = (u16*)  carve((size_t)E*64*2);      // xw / h' in-place
  float* gh    = (float*)carve((size_t)64*192*4);
  u16*   wfs[3];
  for(int l = 0; l < 3; l++) wfs[l] = (u16*)carve((size_t)4096*2);

  kzero<<<(4*N+255)/256, 256, 0, stream>>>(deg0, 4*N);
  kzero<<<(12288+255)/256, 256, 0, stream>>>((int*)gh, 12288);
  kdeg2<<<(E+255)/256, 256, 0, stream>>>(ei0, ei1, deg0, deg1, E);
  ktilesum<<<2*nt, 256, 0, stream>>>(deg0, deg1, tsum, N, nt);
  kmid<<<2, 256, 0, stream>>>(tsum, off0, off1, N, nt);
  kapply<<<2*nt, 256, 0, stream>>>(deg0, deg1, tsum, off0, off1, N, nt);
  kdinv2<<<(N+255)/256, 256, 0, stream>>>(deg0, deg1, dinv, N);
  kperm<<<(E+255)/256, 256, 0, stream>>>(ei0, ei1, nimp, off0, cur0,
                                         eis0, eis1, orig, imp, E);
  kfillv<<<(E+255)/256, 256, 0, stream>>>(eis1, off1, cur1, list1, E);
  kprepw<32><<<1, 256, 0, stream>>>(Ws[0], wfs[0]);
  kprepw<64><<<2, 256, 0, stream>>>(Ws[1], wfs[1]);
  kprepw<64><<<2, 256, 0, stream>>>(Ws[2], wfs[2]);

  const int nbG = (E + 63)/64;
  const int nbA = (N + 3)/4;
  const int nbF = (E + 255)/256;   // contiguous 256-edge chunk per block

  kgemm0<<<nbG, 256, 0, stream>>>(edge_attr, buf, wfs[0], imp, orig, E);
  kagg<<<nbA, 256, 0, stream>>>(buf, off0, off1, list1, heb, N);
  kfused<true ><<<nbF, 256, 0, stream>>>(buf, heb, dinv, eis0, eis1, imp, bs[0],
                                         batch, wfs[1], gh + 0*64, E);
  kagg<<<nbA, 256, 0, stream>>>(buf, off0, off1, list1, heb, N);
  kfused<true ><<<nbF, 256, 0, stream>>>(buf, heb, dinv, eis0, eis1, imp, bs[1],
                                         batch, wfs[2], gh + 1*64, E);
  kagg<<<nbA, 256, 0, stream>>>(buf, off0, off1, list1, heb, N);
  kfused<false><<<nbF, 256, 0, stream>>>(buf, heb, dinv, eis0, eis1, imp, bs[2],
                                         batch, nullptr, gh + 2*64, E);
  kfinal<<<(12288+255)/256, 256, 0, stream>>>(gh, (float*)d_out, 12288);
}

// Round 11
// 506.903 us; speedup vs baseline: 3.1531x; 1.0443x over previous
//
#include <hip/hip_runtime.h>
#include <hip/hip_bf16.h>
#include <cstdint>
#include <cstddef>

typedef unsigned short u16;
typedef unsigned int   u32;
typedef short bf16x8 __attribute__((ext_vector_type(8)));   // 8 bf16 = 4 VGPRs
typedef float f32x4  __attribute__((ext_vector_type(4)));

struct __align__(16) EDesc {        // 32 B per sorted edge, built once
  int u, v; float rc, iurc;
  float ivrc, ie; int bat, pad;
};

__device__ __forceinline__ float bf2f(u16 v){ return __uint_as_float(((u32)v)<<16); }
__device__ __forceinline__ u16 f2bf(float f){
  u32 x = __float_as_uint(f);
  return (u16)((x + 0x7FFFu + ((x>>16)&1u)) >> 16);   // round-to-nearest-even
}
__device__ __forceinline__ void atomAddF(float* p, float v){ unsafeAtomicAdd(p, v); }

// ---------------- zero helper ----------------
__global__ void kzero(int* p, int n){
  int i = blockIdx.x*blockDim.x + threadIdx.x;
  if(i < n) p[i] = 0;
}

// ---------------- per-side degree counts ----------------
__global__ void kdeg2(const int* __restrict__ ei0, const int* __restrict__ ei1,
                      int* __restrict__ deg0, int* __restrict__ deg1, int E){
  int e = blockIdx.x*blockDim.x + threadIdx.x;
  if(e >= E) return;
  atomicAdd(&deg0[ei0[e]], 1);
  atomicAdd(&deg1[ei1[e]], 1);
}

// ---------------- hierarchical exclusive scan (3 phases) ----------------
__global__ __launch_bounds__(256) void ktilesum(const int* __restrict__ deg0,
                                                const int* __restrict__ deg1,
                                                int* __restrict__ tsum,
                                                int N, int nt){
  __shared__ int sh[256];
  const int b = blockIdx.x;
  const int* deg = (b < nt) ? deg0 : deg1;
  const int tile = (b < nt) ? b : b - nt;
  const int t = threadIdx.x;
  const int i = tile*256 + t;
  sh[t] = (i < N) ? deg[i] : 0;
  __syncthreads();
  for(int s = 128; s > 0; s >>= 1){
    if(t < s) sh[t] += sh[t+s];
    __syncthreads();
  }
  if(t == 0) tsum[b] = sh[0];
}
__global__ __launch_bounds__(256) void kmid(int* __restrict__ tsum,
                                            int* __restrict__ off0,
                                            int* __restrict__ off1,
                                            int N, int nt){
  __shared__ int sh[256];
  const int b = blockIdx.x;
  int* ts = tsum + b*nt;
  const int t = threadIdx.x;
  sh[t] = (t < nt) ? ts[t] : 0;
  __syncthreads();
  for(int s = 1; s < 256; s <<= 1){
    int x = (t >= s) ? sh[t-s] : 0;
    __syncthreads();
    sh[t] += x;
    __syncthreads();
  }
  if(t < nt) ts[t] = (t == 0) ? 0 : sh[t-1];
  if(t == 255){ int* off = b ? off1 : off0; off[N] = sh[255]; }
}
// phase 3: intra-tile scan + tile base -> off[]; blocks b<nt also emit dinv
__global__ __launch_bounds__(256) void kapply(const int* __restrict__ deg0,
                                              const int* __restrict__ deg1,
                                              const int* __restrict__ tsum,
                                              int* __restrict__ off0,
                                              int* __restrict__ off1,
                                              float* __restrict__ dinv,
                                              int N, int nt){
  __shared__ int sh[256];
  const int b = blockIdx.x;
  const int* deg = (b < nt) ? deg0 : deg1;
  int*       off = (b < nt) ? off0 : off1;
  const int tile = (b < nt) ? b : b - nt;
  const int base = tsum[b];
  const int t = threadIdx.x;
  const int i = tile*256 + t;
  sh[t] = (i < N) ? deg[i] : 0;
  __syncthreads();
  for(int s = 1; s < 256; s <<= 1){
    int x = (t >= s) ? sh[t-s] : 0;
    __syncthreads();
    sh[t] += x;
    __syncthreads();
  }
  if(i < N){
    off[i] = base + ((t == 0) ? 0 : sh[t-1]);
    if(b < nt){
      int d = deg0[i] + deg1[i];
      dinv[i] = (d > 1) ? (1.f/(float)d) : 0.f;   // deg==1 hyperedges dropped
    }
  }
}

// ---------------- counting-sort + per-edge descriptor ----------------
__global__ void kperm(const int* __restrict__ ei0, const int* __restrict__ ei1,
                      const float* __restrict__ nimp, const float* __restrict__ dinv,
                      const int* __restrict__ batch, const int* __restrict__ off0,
                      int* __restrict__ cur0, EDesc* __restrict__ edesc,
                      int* __restrict__ orig, float* __restrict__ imp, int E){
  int e = blockIdx.x*blockDim.x + threadIdx.x;
  if(e >= E) return;
  int u = ei0[e], v = ei1[e];
  int pos = off0[u] + atomicAdd(&cur0[u], 1);
  float iu = dinv[u], iv = dinv[v];
  float rc = (iu > 0.f && iv > 0.f) ? (1.f/3.f)
           : ((iu > 0.f || iv > 0.f) ? 0.5f : 1.f);
  EDesc d;
  d.u = u; d.v = v; d.rc = rc; d.iurc = iu*rc;
  d.ivrc = iv*rc; d.ie = fminf(nimp[u], nimp[v]); d.bat = batch[u]; d.pad = 0;
  edesc[pos] = d;
  orig[pos]  = e;
  imp[pos]   = d.ie;
}

// ---------------- v-side incidence list (sorted edge ids) ----------------
__global__ void kfillv(const EDesc* __restrict__ edesc, const int* __restrict__ off1,
                       int* __restrict__ cur1, int* __restrict__ list1, int E){
  int p = blockIdx.x*blockDim.x + threadIdx.x;
  if(p >= E) return;
  int v = edesc[p].v;
  list1[off1[v] + atomicAdd(&cur1[v], 1)] = p;
}

// ---------------- W -> fragment-ready layout (all 3 layers, one launch) -------
__global__ void kprepw(const float* __restrict__ W0, u16* __restrict__ wf0,
                       const float* __restrict__ W1, u16* __restrict__ wf1,
                       const float* __restrict__ W2, u16* __restrict__ wf2){
  const int b = blockIdx.x;
  const float* W; u16* wf; int NC, sbase;
  if(b == 0){ W = W0; wf = wf0; NC = 1; sbase = 0; }
  else if(b <= 2){ W = W1; wf = wf1; NC = 2; sbase = (b-1)*256; }
  else { W = W2; wf = wf2; NC = 2; sbase = (b-3)*256; }
  int s = sbase + threadIdx.x;
  if(s >= 4*NC*64) return;
  int lane = s & 63;
  int c    = (s >> 6) % NC;
  int tt   = s / (NC*64);
  int n  = tt*16 + (lane & 15);
  int k0 = c*32 + (lane >> 4)*8;
  #pragma unroll
  for(int j = 0; j < 8; j++)
    wf[(size_t)s*8 + j] = f2bf(W[(size_t)(k0 + j)*64 + n]);
}

// ---------------- layer 0: MFMA GEMM (edge_attr[orig]*imp @ W0) ---------------
__global__ __launch_bounds__(256) void kgemm0(const float* __restrict__ srcf,
                                              u16* __restrict__ buf,
                                              const u16* __restrict__ wf,
                                              const float* __restrict__ imp,
                                              const int* __restrict__ orig,
                                              int E){
  const int t    = threadIdx.x;
  const int wv   = t >> 6;
  const int lane = t & 63;
  const int quad = lane >> 4;
  const int l15  = lane & 15;
  const int row0 = blockIdx.x*64 + wv*16;
  if(row0 >= E) return;                      // E % 16 == 0

  bf16x8 bfr[4];
  #pragma unroll
  for(int i = 0; i < 4; i++)
    bfr[i] = *(const bf16x8*)(wf + ((size_t)i*64 + lane)*8);

  const int myrow = row0 + l15;
  const int oe = orig[myrow];
  const float* s = srcf + (size_t)oe*32 + quad*8;
  const float sc = imp[myrow];
  f32x4 v0 = *(const f32x4*)s;
  f32x4 v1 = *(const f32x4*)(s+4);
  bf16x8 afr;
  afr[0]=(short)f2bf(v0.x*sc); afr[1]=(short)f2bf(v0.y*sc);
  afr[2]=(short)f2bf(v0.z*sc); afr[3]=(short)f2bf(v0.w*sc);
  afr[4]=(short)f2bf(v1.x*sc); afr[5]=(short)f2bf(v1.y*sc);
  afr[6]=(short)f2bf(v1.z*sc); afr[7]=(short)f2bf(v1.w*sc);

  #pragma unroll
  for(int tt = 0; tt < 4; tt++){
    f32x4 a = {0.f,0.f,0.f,0.f};
    a = __builtin_amdgcn_mfma_f32_16x16x32_bf16(afr, bfr[tt], a, 0, 0, 0);
    const int n = tt*16 + l15;
    #pragma unroll
    for(int r = 0; r < 4; r++)
      buf[(size_t)(row0 + quad*4 + r)*64 + n] = f2bf(a[r]);
  }
}

// ---------------- aggregate: 8 rows per wave-instr, col-block layout ----------
// lane = (rsub = lane>>3 row-in-group, cb = lane&7 col-block of 8 cols)
__global__ __launch_bounds__(256) void kagg(const u16* __restrict__ buf,
                                            const int* __restrict__ off0,
                                            const int* __restrict__ off1,
                                            const int* __restrict__ list1,
                                            u16* __restrict__ heb, int N){
  const int t = threadIdx.x, wv = t >> 6, lane = t & 63;
  const int n = blockIdx.x*4 + wv;
  if(n >= N) return;
  const int rsub = lane >> 3, cb = lane & 7;
  float acc[8];
  #pragma unroll
  for(int k = 0; k < 8; k++) acc[k] = 0.f;

  auto accum = [&](uint4 x){
    acc[0] += bf2f((u16)x.x); acc[1] += bf2f((u16)(x.x>>16));
    acc[2] += bf2f((u16)x.y); acc[3] += bf2f((u16)(x.y>>16));
    acc[4] += bf2f((u16)x.z); acc[5] += bf2f((u16)(x.z>>16));
    acc[6] += bf2f((u16)x.w); acc[7] += bf2f((u16)(x.w>>16));
  };
  const uint4 zero4 = {0,0,0,0};

  // u-side: contiguous rows [off0[n], off0[n+1])
  {
    const int s0 = off0[n], d0 = off0[n+1] - s0;
    const u16* base = buf + (size_t)s0*64;
    int j = 0;
    for(; j + 8 <= d0; j += 8)
      accum(*(const uint4*)(base + (size_t)(j+rsub)*64 + cb*8));
    if(j < d0)
      accum((rsub < d0-j) ? *(const uint4*)(base + (size_t)(j+rsub)*64 + cb*8) : zero4);
  }
  // v-side: random rows via list1
  {
    const int s1 = off1[n], d1 = off1[n+1] - s1;
    int j = 0;
    for(; j + 8 <= d1; j += 8){
      int e = list1[s1 + j + rsub];
      accum(*(const uint4*)(buf + (size_t)e*64 + cb*8));
    }
    if(j < d1){
      uint4 x = zero4;
      if(rsub < d1-j){
        int e = list1[s1 + j + rsub];
        x = *(const uint4*)(buf + (size_t)e*64 + cb*8);
      }
      accum(x);
    }
  }
  // reduce across rsub (lanes differing in bits 3..5)
  #pragma unroll
  for(int m = 8; m <= 32; m <<= 1)
    #pragma unroll
    for(int k = 0; k < 8; k++) acc[k] += __shfl_xor(acc[k], m);
  // write: rsub==0 lanes store 8 cols (16 B)
  if(rsub == 0){
    u32 o[4];
    #pragma unroll
    for(int k = 0; k < 4; k++)
      o[k] = (u32)f2bf(acc[2*k]) | ((u32)f2bf(acc[2*k+1]) << 16);
    *(uint4*)(heb + (size_t)n*64 + cb*8) = make_uint4(o[0],o[1],o[2],o[3]);
  }
}

// ---------------- fused: gather + epilogue + register-pool (+ GEMM) ------------
template<bool DO_GEMM>
__global__ __launch_bounds__(256) void kfused(u16* buf,               // r/w
                                              const u16* __restrict__ heb,
                                              const EDesc* __restrict__ edesc,
                                              const float* __restrict__ bias,
                                              const u16* __restrict__ wf,
                                              float* __restrict__ ghL,  // gh + layer*64
                                              int E){
  constexpr int HTSZ = DO_GEMM ? 4*16*72 : 4;       // 16 rows x 72 per wave
  __shared__ __align__(16) u16 hT[HTSZ];
  const int t = threadIdx.x, wv = t >> 6, lane = t & 63;
  const int quad = lane >> 4, l15 = lane & 15;
  const float bd = bias[lane];

  bf16x8 bfr[8];
  if(DO_GEMM){
    #pragma unroll
    for(int i = 0; i < 8; i++)
      bfr[i] = *(const bf16x8*)(wf + ((size_t)i*64 + lane)*8);
  }

  float pool = 0.f;
  int cur_g = -1;

  const int chunk0 = blockIdx.x*256;
  #pragma unroll 1
  for(int it = 0; it < 4; it++){
    const int r0 = chunk0 + it*64 + wv*16;
    if(r0 < E){                                   // E % 16 == 0
      // ---- stage 1: gather + epilogue, 2 groups of 8 edges (ILP-8) ----
      #pragma unroll
      for(int g = 0; g < 2; g++){
        const int e0 = r0 + g*8;
        EDesc ed[8];
        float bv8[8], hu8[8], hv8[8];
        #pragma unroll
        for(int q = 0; q < 8; q++) ed[q] = edesc[e0+q];  // 2x dwordx4 broadcast
        #pragma unroll
        for(int q = 0; q < 8; q++){
          hv8[q] = bf2f(heb[(size_t)ed[q].v*64 + lane]);
          hu8[q] = bf2f(heb[(size_t)ed[q].u*64 + lane]);
          bv8[q] = bf2f(buf[(size_t)(e0+q)*64 + lane]);
        }
        #pragma unroll
        for(int q = 0; q < 8; q++){
          float o = fmaxf(fmaf(bv8[q], ed[q].rc,
                          fmaf(hu8[q], ed[q].iurc,
                          fmaf(hv8[q], ed[q].ivrc, bd))), 0.f) * ed[q].ie;
          if(ed[q].bat != cur_g){                        // wave-uniform branch
            if(cur_g >= 0) atomAddF(&ghL[cur_g*192 + lane], pool);
            pool = 0.f;
            cur_g = ed[q].bat;
          }
          pool += o;
          if(DO_GEMM) hT[wv*1152 + (g*8+q)*72 + lane] = f2bf(o);
        }
      }
      // ---- stage 2: MFMA these 16 rows (wave-local LDS, no barrier) ----
      if(DO_GEMM){
        bf16x8 afr0 = *(const bf16x8*)&hT[wv*1152 + l15*72 + quad*8];
        bf16x8 afr1 = *(const bf16x8*)&hT[wv*1152 + l15*72 + 32 + quad*8];
        #pragma unroll
        for(int tt = 0; tt < 4; tt++){
          f32x4 a = {0.f,0.f,0.f,0.f};
          a = __builtin_amdgcn_mfma_f32_16x16x32_bf16(afr0, bfr[tt*2+0], a, 0, 0, 0);
          a = __builtin_amdgcn_mfma_f32_16x16x32_bf16(afr1, bfr[tt*2+1], a, 0, 0, 0);
          const int n = tt*16 + l15;
          #pragma unroll
          for(int r = 0; r < 4; r++)
            buf[(size_t)(r0 + quad*4 + r)*64 + n] = f2bf(a[r]);
        }
      }
    }
  }
  if(cur_g >= 0) atomAddF(&ghL[cur_g*192 + lane], pool);
}

__global__ void kfinal(const float* __restrict__ gh, float* __restrict__ out, int n){
  int i = blockIdx.x*blockDim.x + threadIdx.x;
  if(i < n) out[i] = gh[i];   // reference output dtype = float32
}

// ---------------- host ----------------
extern "C" void kernel_launch(void* const* d_in, const int* in_sizes, int n_in,
                              void* d_out, int out_size, void* d_ws, size_t ws_size,
                              hipStream_t stream) {
  const float* edge_attr = (const float*)d_in[1];
  const int*   ei        = (const int*)d_in[2];
  const int*   batch     = (const int*)d_in[3];
  const float* nimp      = (const float*)d_in[4];
  const float* Ws[3] = { (const float*)d_in[5], (const float*)d_in[7], (const float*)d_in[9] };
  const float* bs[3] = { (const float*)d_in[6], (const float*)d_in[8], (const float*)d_in[10] };

  const int E = in_sizes[1] / 32;   // edge_attr is (E, 32)
  const int N = in_sizes[4];        // node_imp is (N,)
  const int* ei0 = ei;
  const int* ei1 = ei + E;

  char* p = (char*)d_ws;
  auto carve = [&](size_t bytes)->char*{
    char* r = p; p += (bytes + 255) & ~(size_t)255; return r;
  };
  const int nt = (N + 255)/256;
  float* imp   = (float*)carve((size_t)E*4);
  int*   deg0  = (int*)  carve((size_t)4*N*4);       // deg0|deg1|cur0|cur1
  int*   deg1  = deg0 + N;
  int*   cur0  = deg0 + 2*N;
  int*   cur1  = deg0 + 3*N;
  float* dinv  = (float*)carve((size_t)N*4);
  int*   off0  = (int*)  carve((size_t)(N+1)*4);
  int*   off1  = (int*)  carve((size_t)(N+1)*4);
  int*   tsum  = (int*)  carve((size_t)2*nt*4);
  int*   orig  = (int*)  carve((size_t)E*4);
  int*   list1 = (int*)  carve((size_t)E*4);
  EDesc* edesc = (EDesc*)carve((size_t)E*sizeof(EDesc));
  u16*   heb   = (u16*)  carve((size_t)N*64*2);
  u16*   buf   = (u16*)  carve((size_t)E*64*2);      // xw / h' in-place
  float* gh    = (float*)carve((size_t)64*192*4);
  u16*   wfs[3];
  for(int l = 0; l < 3; l++) wfs[l] = (u16*)carve((size_t)4096*2);

  kzero<<<(4*N+255)/256, 256, 0, stream>>>(deg0, 4*N);
  kzero<<<(12288+255)/256, 256, 0, stream>>>((int*)gh, 12288);
  kdeg2<<<(E+255)/256, 256, 0, stream>>>(ei0, ei1, deg0, deg1, E);
  ktilesum<<<2*nt, 256, 0, stream>>>(deg0, deg1, tsum, N, nt);
  kmid<<<2, 256, 0, stream>>>(tsum, off0, off1, N, nt);
  kapply<<<2*nt, 256, 0, stream>>>(deg0, deg1, tsum, off0, off1, dinv, N, nt);
  kperm<<<(E+255)/256, 256, 0, stream>>>(ei0, ei1, nimp, dinv, batch, off0, cur0,
                                         edesc, orig, imp, E);
  kfillv<<<(E+255)/256, 256, 0, stream>>>(edesc, off1, cur1, list1, E);
  kprepw<<<5, 256, 0, stream>>>(Ws[0], wfs[0], Ws[1], wfs[1], Ws[2], wfs[2]);

  const int nbG = (E + 63)/64;
  const int nbA = (N + 3)/4;
  const int nbF = (E + 255)/256;   // contiguous 256-edge chunk per block

  kgemm0<<<nbG, 256, 0, stream>>>(edge_attr, buf, wfs[0], imp, orig, E);
  kagg<<<nbA, 256, 0, stream>>>(buf, off0, off1, list1, heb, N);
  kfused<true ><<<nbF, 256, 0, stream>>>(buf, heb, edesc, bs[0], wfs[1], gh + 0*64, E);
  kagg<<<nbA, 256, 0, stream>>>(buf, off0, off1, list1, heb, N);
  kfused<true ><<<nbF, 256, 0, stream>>>(buf, heb, edesc, bs[1], wfs[2], gh + 1*64, E);
  kagg<<<nbA, 256, 0, stream>>>(buf, off0, off1, list1, heb, N);
  kfused<false><<<nbF, 256, 0, stream>>>(buf, heb, edesc, bs[2], nullptr, gh + 2*64, E);
  kfinal<<<(12288+255)/256, 256, 0, stream>>>(gh, (float*)d_out, 12288);
}